// Round 2
// baseline (653.737 us; speedup 1.0000x reference)
//
#include <hip/hip_runtime.h>
#include <hip/hip_bf16.h>

#define NN    50000
#define NUSER 40000
#define EE    400000
#define KKIND 3
#define HHEAD 4
#define FIN   128
#define FOUT  64
#define NCLS  40

typedef __attribute__((ext_vector_type(8))) short short8;
typedef __attribute__((ext_vector_type(4))) float floatx4;

__device__ __forceinline__ float bf2f(unsigned short u) {
    unsigned int v = ((unsigned int)u) << 16;
    return __uint_as_float(v);
}
__device__ __forceinline__ unsigned short f2bf(float f) {
    unsigned int u = __float_as_uint(f);
    unsigned int r = (u + 0x7FFFu + ((u >> 16) & 1u)) >> 16;  // RNE
    return (unsigned short)r;
}

// conv-region element offsets (u16 elements)
#define OFF_H    0
#define OFF_W    6400000
#define OFF_ASRC 6498304
#define OFF_ATRG 6499072
#define OFF_W1   6499840
#define OFF_W2   6508032
#define OFF_M    6512128
#define OFF_FCW  6512192
#define OFF_FCB  6522432
#define CONV_TOT 6522472

// ---------------------------------------------------------------------------
// detect: are float inputs f32 (flag=1) or bf16 (flag=0)?  Scan h's first
// 2048 u16s for wild exponent fields (|x| >= 2^17) — impossible for bf16
// N(0,1) data, ~44% of the f32 mantissa-low-halves.
// ---------------------------------------------------------------------------
__global__ __launch_bounds__(256) void detect_kernel(const unsigned short* __restrict__ hraw,
                                                     int* __restrict__ flag)
{
    __shared__ int cnt;
    if (threadIdx.x == 0) cnt = 0;
    __syncthreads();
    int local = 0;
#pragma unroll
    for (int j = 0; j < 8; j++) {
        unsigned short u = hraw[threadIdx.x * 8 + j];
        int ex = (u >> 7) & 0xFF;
        if (ex >= 0x90) local++;
    }
    atomicAdd(&cnt, local);
    __syncthreads();
    if (threadIdx.x == 0) *flag = (cnt > 100) ? 1 : 0;
}

// ---------------------------------------------------------------------------
// canonicalize all float inputs into bf16 conv region
// ---------------------------------------------------------------------------
__global__ __launch_bounds__(256) void conv_kernel(const void* __restrict__ p0, const void* __restrict__ p2,
                                                   const void* __restrict__ p3, const void* __restrict__ p4,
                                                   const void* __restrict__ p5, const void* __restrict__ p6,
                                                   const void* __restrict__ p7, const void* __restrict__ p8,
                                                   const void* __restrict__ p9,
                                                   const int* __restrict__ flagp,
                                                   unsigned short* __restrict__ dst)
{
    int tid = blockIdx.x * 256 + threadIdx.x;
    if (tid >= CONV_TOT) return;
    const void* src; int li;
    if      (tid < OFF_W)    { src = p0; li = tid - OFF_H; }
    else if (tid < OFF_ASRC) { src = p2; li = tid - OFF_W; }
    else if (tid < OFF_ATRG) { src = p3; li = tid - OFF_ASRC; }
    else if (tid < OFF_W1)   { src = p4; li = tid - OFF_ATRG; }
    else if (tid < OFF_W2)   { src = p5; li = tid - OFF_W1; }
    else if (tid < OFF_M)    { src = p6; li = tid - OFF_W2; }
    else if (tid < OFF_FCW)  { src = p7; li = tid - OFF_M; }
    else if (tid < OFF_FCB)  { src = p8; li = tid - OFF_FCW; }
    else                     { src = p9; li = tid - OFF_FCB; }
    unsigned short v;
    if (*flagp) v = f2bf(((const float*)src)[li]);
    else        v = ((const unsigned short*)src)[li];
    dst[tid] = v;
}

// ---------------------------------------------------------------------------
// hp = h @ w[k]  -> (NN, 256) bf16.  One wave per 16-row m-tile, all 256 cols.
// ---------------------------------------------------------------------------
__global__ __launch_bounds__(256) void hp_gemm(const unsigned short* __restrict__ h,
                                               const unsigned short* __restrict__ wk,
                                               unsigned short* __restrict__ hp)
{
    int wave = (blockIdx.x * 256 + threadIdx.x) >> 6;
    int lane = threadIdx.x & 63;
    if (wave >= NN / 16) return;
    int m0 = wave * 16;
    int mi = lane & 15, quad = lane >> 4;

    short8 a[4];
    const unsigned short* hrow = h + (size_t)(m0 + mi) * FIN + quad * 8;
#pragma unroll
    for (int kk = 0; kk < 4; kk++) a[kk] = *(const short8*)(hrow + kk * 32);

    for (int nt = 0; nt < 16; nt++) {
        int c = nt * 16 + mi;            // output column (0..255)
        int hh = c >> 6, f = c & 63;
        const unsigned short* bcol = wk + hh * (FIN * FOUT) + f;  // + d*64
        floatx4 acc = {0.f, 0.f, 0.f, 0.f};
#pragma unroll
        for (int kk = 0; kk < 4; kk++) {
            int dbase = kk * 32 + quad * 8;
            short8 b;
#pragma unroll
            for (int j = 0; j < 8; j++) b[j] = (short)bcol[(dbase + j) * FOUT];
            acc = __builtin_amdgcn_mfma_f32_16x16x32_bf16(a[kk], b, acc, 0, 0, 0);
        }
#pragma unroll
        for (int reg = 0; reg < 4; reg++) {
            int rr = m0 + quad * 4 + reg;
            hp[(size_t)rr * 256 + c] = f2bf(acc[reg]);
        }
    }
}

// ---------------------------------------------------------------------------
// s[n][h] = hp[n][h] . a_src[h],  t likewise.  One wave per node row.
// ---------------------------------------------------------------------------
__global__ __launch_bounds__(256) void st_kernel(const unsigned short* __restrict__ hp,
                                                 const unsigned short* __restrict__ ask,
                                                 const unsigned short* __restrict__ atk,
                                                 float* __restrict__ s, float* __restrict__ t)
{
    int n = blockIdx.x * 4 + (threadIdx.x >> 6);
    int lane = threadIdx.x & 63;
    int c0 = lane * 4;
    int hh = c0 >> 6, f0 = c0 & 63;
    const unsigned short* row = hp + (size_t)n * 256 + c0;
    float v0 = bf2f(row[0]), v1 = bf2f(row[1]), v2 = bf2f(row[2]), v3 = bf2f(row[3]);
    const unsigned short* as = ask + hh * 64 + f0;
    const unsigned short* at = atk + hh * 64 + f0;
    float sp = v0 * bf2f(as[0]) + v1 * bf2f(as[1]) + v2 * bf2f(as[2]) + v3 * bf2f(as[3]);
    float tp = v0 * bf2f(at[0]) + v1 * bf2f(at[1]) + v2 * bf2f(at[2]) + v3 * bf2f(at[3]);
#pragma unroll
    for (int off = 1; off < 16; off <<= 1) {
        sp += __shfl_xor(sp, off, 64);
        tp += __shfl_xor(tp, off, 64);
    }
    if ((lane & 15) == 0) { s[n * 4 + hh] = sp; t[n * 4 + hh] = tp; }
}

// ---------------------------------------------------------------------------
// pass A: exp_e[e][h] = exp(leaky(s[src]+t[trg])); denom[trg][h] += exp_e
// (global max-shift cancels in alpha; skipped)
// ---------------------------------------------------------------------------
__global__ __launch_bounds__(256) void passA(const int* __restrict__ srcI, const int* __restrict__ trgI,
                                             const float* __restrict__ s, const float* __restrict__ t,
                                             float* __restrict__ exp_e, float* __restrict__ denom)
{
    int tid = blockIdx.x * 256 + threadIdx.x;
    int e = tid >> 2, hh = tid & 3;
    int sn = srcI[e], tn = trgI[e];
    float v = s[sn * 4 + hh] + t[tn * 4 + hh];
    v = (v >= 0.f) ? v : 0.2f * v;
    float ex = __expf(v);
    exp_e[tid] = ex;
    atomicAdd(&denom[tn * 4 + hh], ex);
}

// ---------------------------------------------------------------------------
// pass B: ta[trg][f] += 0.25 * sum_h alpha_h * hp[src][h*64+f].  Wave per edge.
// ---------------------------------------------------------------------------
__global__ __launch_bounds__(256) void passB(const int* __restrict__ srcI, const int* __restrict__ trgI,
                                             const float* __restrict__ exp_e, const float* __restrict__ denom,
                                             const unsigned short* __restrict__ hp,
                                             float* __restrict__ ta)
{
    int e = blockIdx.x * 4 + (threadIdx.x >> 6);
    int f = threadIdx.x & 63;
    int sn = srcI[e], tn = trgI[e];
    float aval = 0.f;
    if (f < 4) aval = exp_e[e * 4 + f] / (denom[tn * 4 + f] + 1e-16f);
    float sum = 0.f;
#pragma unroll
    for (int hh = 0; hh < 4; hh++) {
        float a = __shfl(aval, hh, 64);
        sum += a * bf2f(hp[(size_t)sn * 256 + hh * 64 + f]);
    }
    atomicAdd(&ta[(size_t)tn * 64 + f], 0.25f * sum);
}

// ---------------------------------------------------------------------------
// plain C(Mx64) = A(M x Ka bf16, lda) @ B(Ka x 64 bf16) -> f32
// ---------------------------------------------------------------------------
__global__ __launch_bounds__(256) void gemm64(const unsigned short* __restrict__ A, int lda, int Ka,
                                              const unsigned short* __restrict__ B,
                                              float* __restrict__ C, int M)
{
    int wave = (blockIdx.x * 256 + threadIdx.x) >> 6;
    int lane = threadIdx.x & 63;
    int m0 = wave * 16;
    if (m0 >= M) return;
    int mi = lane & 15, quad = lane >> 4;
    int nks = Ka >> 5;
    floatx4 acc[4];
#pragma unroll
    for (int nt = 0; nt < 4; nt++) acc[nt] = (floatx4){0.f, 0.f, 0.f, 0.f};
    for (int kk = 0; kk < nks; kk++) {
        short8 a = *(const short8*)(A + (size_t)(m0 + mi) * lda + kk * 32 + quad * 8);
#pragma unroll
        for (int nt = 0; nt < 4; nt++) {
            const unsigned short* bp = B + (kk * 32 + quad * 8) * 64 + nt * 16 + mi;
            short8 b;
#pragma unroll
            for (int j = 0; j < 8; j++) b[j] = (short)bp[j * 64];
            acc[nt] = __builtin_amdgcn_mfma_f32_16x16x32_bf16(a, b, acc[nt], 0, 0, 0);
        }
    }
#pragma unroll
    for (int nt = 0; nt < 4; nt++)
#pragma unroll
        for (int reg = 0; reg < 4; reg++)
            C[(size_t)(m0 + quad * 4 + reg) * 64 + nt * 16 + mi] = acc[nt][reg];
}

// ---------------------------------------------------------------------------
// ret[:, 0:192] = bf16(ta)  (transpose k-slices into row-contiguous layout)
// ---------------------------------------------------------------------------
__global__ __launch_bounds__(256) void cvt_ta(const float* __restrict__ ta, unsigned short* __restrict__ ret)
{
    int tid = blockIdx.x * 256 + threadIdx.x;   // over NUSER*192
    int n = tid / 192;
    int c = tid - n * 192;
    int k = c >> 6, f = c & 63;
    ret[(size_t)n * 256 + c] = f2bf(ta[((size_t)k * NN + n) * 64 + f]);
}

// ---------------------------------------------------------------------------
// scores[n][k] = sum_f tanh( fw1[n][f] + (ta_k @ w2)[n][f] ) * m[f]
// ---------------------------------------------------------------------------
__global__ __launch_bounds__(256) void qscore_gemm(const unsigned short* __restrict__ retA,
                                                   const unsigned short* __restrict__ w2,
                                                   const float* __restrict__ fw1,
                                                   const unsigned short* __restrict__ mvec,
                                                   float* __restrict__ scores, int M)
{
    int k = blockIdx.y;
    int wave = (blockIdx.x * 256 + threadIdx.x) >> 6;
    int lane = threadIdx.x & 63;
    int m0 = wave * 16;
    if (m0 >= M) return;
    int mi = lane & 15, quad = lane >> 4;
    const unsigned short* A = retA + k * 64;
    floatx4 acc[4];
#pragma unroll
    for (int nt = 0; nt < 4; nt++) acc[nt] = (floatx4){0.f, 0.f, 0.f, 0.f};
#pragma unroll
    for (int kk = 0; kk < 2; kk++) {
        short8 a = *(const short8*)(A + (size_t)(m0 + mi) * 256 + kk * 32 + quad * 8);
#pragma unroll
        for (int nt = 0; nt < 4; nt++) {
            const unsigned short* bp = w2 + (kk * 32 + quad * 8) * 64 + nt * 16 + mi;
            short8 b;
#pragma unroll
            for (int j = 0; j < 8; j++) b[j] = (short)bp[j * 64];
            acc[nt] = __builtin_amdgcn_mfma_f32_16x16x32_bf16(a, b, acc[nt], 0, 0, 0);
        }
    }
    float part[4] = {0.f, 0.f, 0.f, 0.f};
#pragma unroll
    for (int nt = 0; nt < 4; nt++) {
        int col = nt * 16 + mi;
        float mval = bf2f(mvec[col]);
#pragma unroll
        for (int reg = 0; reg < 4; reg++) {
            int rowg = m0 + quad * 4 + reg;
            float q = tanhf(acc[nt][reg] + fw1[(size_t)rowg * 64 + col]);
            part[reg] += q * mval;
        }
    }
#pragma unroll
    for (int off = 1; off < 16; off <<= 1)
#pragma unroll
        for (int reg = 0; reg < 4; reg++) part[reg] += __shfl_xor(part[reg], off, 64);
    if (mi == 0) {
#pragma unroll
        for (int reg = 0; reg < 4; reg++)
            scores[(size_t)(m0 + quad * 4 + reg) * 3 + k] = part[reg];
    }
}

// ---------------------------------------------------------------------------
// beta = softmax(scores); ret[:,192:256] = bf16(sum_k beta_k * ta_k)
// ---------------------------------------------------------------------------
__global__ __launch_bounds__(256) void fuse_kernel(const float* __restrict__ scores,
                                                   const float* __restrict__ ta,
                                                   unsigned short* __restrict__ ret)
{
    int n = blockIdx.x * 4 + (threadIdx.x >> 6);
    int f = threadIdx.x & 63;
    float s0 = scores[n * 3 + 0], s1 = scores[n * 3 + 1], s2 = scores[n * 3 + 2];
    float mx = fmaxf(s0, fmaxf(s1, s2));
    float e0 = __expf(s0 - mx), e1 = __expf(s1 - mx), e2 = __expf(s2 - mx);
    float inv = 1.f / (e0 + e1 + e2);
    float fu = (e0 * ta[((size_t)0 * NN + n) * 64 + f] +
                e1 * ta[((size_t)1 * NN + n) * 64 + f] +
                e2 * ta[((size_t)2 * NN + n) * 64 + f]) * inv;
    ret[(size_t)n * 256 + 192 + f] = f2bf(fu);
}

// ---------------------------------------------------------------------------
// logits = ret(M x 256) @ fc_w(256 x 40) + fc_b -> f32
// ---------------------------------------------------------------------------
__global__ __launch_bounds__(256) void fc_gemm(const unsigned short* __restrict__ A,
                                               const unsigned short* __restrict__ B,
                                               const unsigned short* __restrict__ bias,
                                               float* __restrict__ C, int M)
{
    int wave = (blockIdx.x * 256 + threadIdx.x) >> 6;
    int lane = threadIdx.x & 63;
    int m0 = wave * 16;
    if (m0 >= M) return;
    int mi = lane & 15, quad = lane >> 4;
    floatx4 acc[3];
#pragma unroll
    for (int nt = 0; nt < 3; nt++) acc[nt] = (floatx4){0.f, 0.f, 0.f, 0.f};
#pragma unroll
    for (int kk = 0; kk < 8; kk++) {
        short8 a = *(const short8*)(A + (size_t)(m0 + mi) * 256 + kk * 32 + quad * 8);
#pragma unroll
        for (int nt = 0; nt < 3; nt++) {
            int col = nt * 16 + mi;
            short8 b;
            if (col < NCLS) {
                const unsigned short* bp = B + (kk * 32 + quad * 8) * NCLS + col;
#pragma unroll
                for (int j = 0; j < 8; j++) b[j] = (short)bp[j * NCLS];
            } else {
#pragma unroll
                for (int j = 0; j < 8; j++) b[j] = 0;
            }
            acc[nt] = __builtin_amdgcn_mfma_f32_16x16x32_bf16(a, b, acc[nt], 0, 0, 0);
        }
    }
#pragma unroll
    for (int nt = 0; nt < 3; nt++) {
        int col = nt * 16 + mi;
        if (col < NCLS) {
            float bv = bf2f(bias[col]);
#pragma unroll
            for (int reg = 0; reg < 4; reg++)
                C[(size_t)(m0 + quad * 4 + reg) * NCLS + col] = acc[nt][reg] + bv;
        }
    }
}

// ---------------------------------------------------------------------------
// out = log_softmax(logits); dtype per flag.  Wave per row.
// ---------------------------------------------------------------------------
__global__ __launch_bounds__(256) void lsm_kernel(const float* __restrict__ logits,
                                                  const int* __restrict__ flagp,
                                                  void* __restrict__ out)
{
    int n = blockIdx.x * 4 + (threadIdx.x >> 6);
    int lane = threadIdx.x & 63;
    float v = (lane < NCLS) ? logits[(size_t)n * NCLS + lane] : -3.4e38f;
    float mx = v;
#pragma unroll
    for (int off = 32; off; off >>= 1) mx = fmaxf(mx, __shfl_xor(mx, off, 64));
    float ex = (lane < NCLS) ? __expf(v - mx) : 0.f;
    float sm = ex;
#pragma unroll
    for (int off = 32; off; off >>= 1) sm += __shfl_xor(sm, off, 64);
    float ls = v - mx - logf(sm);
    if (lane < NCLS) {
        size_t idx = (size_t)n * NCLS + lane;
        if (*flagp) ((float*)out)[idx] = ls;
        else        ((unsigned short*)out)[idx] = f2bf(ls);
    }
}

extern "C" void kernel_launch(void* const* d_in, const int* in_sizes, int n_in,
                              void* d_out, int out_size, void* d_ws, size_t ws_size,
                              hipStream_t stream)
{
    (void)in_sizes; (void)n_in; (void)out_size; (void)ws_size;
    const int* ei = (const int*)d_in[1];

    char* ws = (char*)d_ws;
    // canonical bf16 inputs:        [0 .. 13,044,944)
    unsigned short* conv = (unsigned short*)ws;
    unsigned short* hc   = conv + OFF_H;
    unsigned short* wc   = conv + OFF_W;
    unsigned short* asrc = conv + OFF_ASRC;
    unsigned short* atrg = conv + OFF_ATRG;
    unsigned short* w1c  = conv + OFF_W1;
    unsigned short* w2c  = conv + OFF_W2;
    unsigned short* mc   = conv + OFF_M;
    unsigned short* fcwc = conv + OFF_FCW;
    unsigned short* fcbc = conv + OFF_FCB;
    int* flag = (int*)(ws + 13044944);
    // persistent ta:                [13,045,248 .. 51,445,248)
    float* ta = (float*)(ws + 13045248);
    char* R = ws + 51445248;                                  // overlay base
    // per-kind phase layout
    unsigned short* hp = (unsigned short*)R;                  // 25,600,000 B
    float* exp_e = (float*)(R + 25600000);                    //  6,400,000 B
    float* sbuf  = (float*)(R + 32000000);                    //    800,000 B
    float* tbuf  = (float*)(R + 32800000);                    //    800,000 B
    float* denom = (float*)(R + 33600000);                    //    800,000 B
    // final phase overlay (per-kind buffers dead by then)
    float* fw1            = (float*)R;                        // 10,240,000 B
    float* scores         = (float*)(R + 10240000);           //    480,000 B
    float* logits         = (float*)(R + 10720000);           //  6,400,000 B
    unsigned short* ret   = (unsigned short*)(R + 17120000);  // 20,480,000 B

    detect_kernel<<<1, 256, 0, stream>>>((const unsigned short*)d_in[0], flag);
    conv_kernel<<<(CONV_TOT + 255) / 256, 256, 0, stream>>>(
        d_in[0], d_in[2], d_in[3], d_in[4], d_in[5], d_in[6], d_in[7], d_in[8], d_in[9],
        flag, conv);

    hipMemsetAsync(ta, 0, (size_t)KKIND * NN * FOUT * 4, stream);

    for (int k = 0; k < KKIND; k++) {
        const unsigned short* wk = wc + (size_t)k * HHEAD * FIN * FOUT;
        const int* srcI = ei + (size_t)k * 2 * EE;
        const int* trgI = srcI + EE;
        hp_gemm<<<782, 256, 0, stream>>>(hc, wk, hp);
        st_kernel<<<NN / 4, 256, 0, stream>>>(hp, asrc + k * HHEAD * FOUT, atrg + k * HHEAD * FOUT, sbuf, tbuf);
        hipMemsetAsync(denom, 0, (size_t)NN * HHEAD * 4, stream);
        passA<<<EE * HHEAD / 256, 256, 0, stream>>>(srcI, trgI, sbuf, tbuf, exp_e, denom);
        passB<<<EE / 4, 256, 0, stream>>>(srcI, trgI, exp_e, denom, hp, ta + (size_t)k * NN * FOUT);
    }

    gemm64<<<625, 256, 0, stream>>>(hc, FIN, FIN, w1c, fw1, NUSER);
    cvt_ta<<<NUSER * 192 / 256, 256, 0, stream>>>(ta, ret);
    qscore_gemm<<<dim3(625, 3), 256, 0, stream>>>(ret, w2c, fw1, mc, scores, NUSER);
    fuse_kernel<<<NUSER / 4, 256, 0, stream>>>(scores, ta, ret);
    fc_gemm<<<625, 256, 0, stream>>>(ret, fcwc, fcbc, logits, NUSER);
    lsm_kernel<<<NUSER / 4, 256, 0, stream>>>(logits, flag, d_out);
}

// Round 3
// 640.543 us; speedup vs baseline: 1.0206x; 1.0206x over previous
//
#include <hip/hip_runtime.h>
#include <hip/hip_bf16.h>

#define NN    50000
#define NUSER 40000
#define EE    400000
#define KKIND 3
#define HHEAD 4
#define FIN   128
#define FOUT  64
#define NCLS  40

typedef __attribute__((ext_vector_type(8))) short short8;
typedef __attribute__((ext_vector_type(4))) float floatx4;

__device__ __forceinline__ float bf2f(unsigned short u) {
    unsigned int v = ((unsigned int)u) << 16;
    return __uint_as_float(v);
}
__device__ __forceinline__ unsigned short f2bf(float f) {
    unsigned int u = __float_as_uint(f);
    unsigned int r = (u + 0x7FFFu + ((u >> 16) & 1u)) >> 16;  // RNE
    return (unsigned short)r;
}

// conv-region element offsets (u16 elements)
#define OFF_H    0
#define OFF_W    6400000
#define OFF_ASRC 6498304
#define OFF_ATRG 6499072
#define OFF_W1   6499840
#define OFF_W2   6508032
#define OFF_M    6512128
#define OFF_FCW  6512192
#define OFF_FCB  6522432
#define CONV_TOT 6522472

// ---------------------------------------------------------------------------
// dtype detect (f32 vs bf16 float inputs)
// ---------------------------------------------------------------------------
__global__ __launch_bounds__(256) void detect_kernel(const unsigned short* __restrict__ hraw,
                                                     int* __restrict__ flag)
{
    __shared__ int cnt;
    if (threadIdx.x == 0) cnt = 0;
    __syncthreads();
    int local = 0;
#pragma unroll
    for (int j = 0; j < 8; j++) {
        unsigned short u = hraw[threadIdx.x * 8 + j];
        int ex = (u >> 7) & 0xFF;
        if (ex >= 0x90) local++;
    }
    atomicAdd(&cnt, local);
    __syncthreads();
    if (threadIdx.x == 0) *flag = (cnt > 100) ? 1 : 0;
}

__global__ __launch_bounds__(256) void conv_kernel(const void* __restrict__ p0, const void* __restrict__ p2,
                                                   const void* __restrict__ p3, const void* __restrict__ p4,
                                                   const void* __restrict__ p5, const void* __restrict__ p6,
                                                   const void* __restrict__ p7, const void* __restrict__ p8,
                                                   const void* __restrict__ p9,
                                                   const int* __restrict__ flagp,
                                                   unsigned short* __restrict__ dst)
{
    int tid = blockIdx.x * 256 + threadIdx.x;
    if (tid >= CONV_TOT) return;
    const void* src; int li;
    if      (tid < OFF_W)    { src = p0; li = tid - OFF_H; }
    else if (tid < OFF_ASRC) { src = p2; li = tid - OFF_W; }
    else if (tid < OFF_ATRG) { src = p3; li = tid - OFF_ASRC; }
    else if (tid < OFF_W1)   { src = p4; li = tid - OFF_ATRG; }
    else if (tid < OFF_W2)   { src = p5; li = tid - OFF_W1; }
    else if (tid < OFF_M)    { src = p6; li = tid - OFF_W2; }
    else if (tid < OFF_FCW)  { src = p7; li = tid - OFF_M; }
    else if (tid < OFF_FCB)  { src = p8; li = tid - OFF_FCW; }
    else                     { src = p9; li = tid - OFF_FCB; }
    unsigned short v;
    if (*flagp) v = f2bf(((const float*)src)[li]);
    else        v = ((const unsigned short*)src)[li];
    dst[tid] = v;
}

// ---------------------------------------------------------------------------
// B-matrix repacks into MFMA fragment layout (one coalesced 16B load / frag)
// ---------------------------------------------------------------------------
// w (per kind, per head 128x64) -> wT[k][h][g][f][8], g = kk*4+quad in [0,16)
__global__ __launch_bounds__(256) void repack_w(const unsigned short* __restrict__ w,
                                                unsigned short* __restrict__ wT)
{
    int tid = blockIdx.x * 256 + threadIdx.x;       // 3*4*16*64 = 12288
    if (tid >= 12288) return;
    int f = tid & 63, g = (tid >> 6) & 15, h = (tid >> 10) & 3, k = tid >> 12;
    const unsigned short* src = w + (size_t)(k * 4 + h) * 8192 + f;
    unsigned short* dst = wT + (size_t)tid * 8;
#pragma unroll
    for (int j = 0; j < 8; j++) dst[j] = src[(size_t)(g * 8 + j) * 64];
}

// w1 (128x64), w2 (64x64), fcw (256x40 -> pad 48)
__global__ __launch_bounds__(256) void repack_small(const unsigned short* __restrict__ w1,
                                                    const unsigned short* __restrict__ w2,
                                                    const unsigned short* __restrict__ fcw,
                                                    unsigned short* __restrict__ w1T,
                                                    unsigned short* __restrict__ w2T,
                                                    unsigned short* __restrict__ fcwT)
{
    int tid = blockIdx.x * 256 + threadIdx.x;
    if (tid < 1024) {                                 // w1: g in [0,16), c in [0,64)
        int c = tid & 63, g = tid >> 6;
#pragma unroll
        for (int j = 0; j < 8; j++) w1T[(size_t)(g * 64 + c) * 8 + j] = w1[(size_t)(g * 8 + j) * 64 + c];
    } else if (tid < 1536) {                          // w2: g in [0,8)
        int t = tid - 1024; int c = t & 63, g = t >> 6;
#pragma unroll
        for (int j = 0; j < 8; j++) w2T[(size_t)(g * 64 + c) * 8 + j] = w2[(size_t)(g * 8 + j) * 64 + c];
    } else if (tid < 3072) {                          // fcw: g in [0,32), c in [0,48)
        int t = tid - 1536; int c = t % 48, g = t / 48;
#pragma unroll
        for (int j = 0; j < 8; j++)
            fcwT[(size_t)(g * 48 + c) * 8 + j] = (c < NCLS) ? fcw[(size_t)(g * 8 + j) * NCLS + c] : (unsigned short)0;
    }
}

// ---------------------------------------------------------------------------
// CSR sort of edges by target (targets < NUSER only), all 3 kinds at once
// ---------------------------------------------------------------------------
__global__ __launch_bounds__(256) void hist3(const int* __restrict__ ei, unsigned int* __restrict__ cnt)
{
    int e = blockIdx.x * 256 + threadIdx.x;
    int k = blockIdx.y;
    if (e >= EE) return;
    int tn = ei[(size_t)k * 2 * EE + EE + e];
    if (tn < NUSER) atomicAdd(&cnt[(size_t)k * NUSER + tn], 1u);
}

__global__ __launch_bounds__(1024) void scan3(const unsigned int* __restrict__ cnt,
                                              unsigned int* __restrict__ rowptr)
{
    int k = blockIdx.x;
    const unsigned int* c = cnt + (size_t)k * NUSER;
    unsigned int* rp = rowptr + (size_t)k * (NUSER + 1);
    int lane = threadIdx.x & 63, wid = threadIdx.x >> 6;
    const int CH = 40;                                 // 1024*40 >= 40000
    int base = threadIdx.x * CH;
    unsigned int s = 0;
#pragma unroll 4
    for (int i = 0; i < CH; i++) { int idx = base + i; if (idx < NUSER) s += c[idx]; }
    unsigned int v = s;
#pragma unroll
    for (int off = 1; off < 64; off <<= 1) { unsigned int u = __shfl_up(v, off, 64); if (lane >= off) v += u; }
    __shared__ unsigned int wsum[16];
    if (lane == 63) wsum[wid] = v;
    __syncthreads();
    if (wid == 0) {
        unsigned int x = (lane < 16) ? wsum[lane] : 0u;
#pragma unroll
        for (int off = 1; off < 16; off <<= 1) { unsigned int u = __shfl_up(x, off, 64); if (lane >= off) x += u; }
        if (lane < 16) wsum[lane] = x;                 // inclusive per-wave sums
    }
    __syncthreads();
    unsigned int run = (v - s) + (wid ? wsum[wid - 1] : 0u);
    for (int i = 0; i < CH; i++) {
        int idx = base + i;
        if (idx < NUSER) { rp[idx] = run; run += c[idx]; }
    }
    if (threadIdx.x == 1023) rp[NUSER] = wsum[15];
}

__global__ __launch_bounds__(256) void scatter3(const int* __restrict__ ei,
                                                const unsigned int* __restrict__ rowptr,
                                                unsigned int* __restrict__ off,
                                                int* __restrict__ srcl)
{
    int e = blockIdx.x * 256 + threadIdx.x;
    int k = blockIdx.y;
    if (e >= EE) return;
    const int* srcA = ei + (size_t)k * 2 * EE;
    int tn = srcA[EE + e];
    if (tn >= NUSER) return;
    unsigned int p = rowptr[(size_t)k * (NUSER + 1) + tn] + atomicAdd(&off[(size_t)k * NUSER + tn], 1u);
    srcl[(size_t)k * EE + p] = srcA[e];
}

// ---------------------------------------------------------------------------
// hp2 = h @ w[k] in layout [n][f][4heads] bf16, with fused s/t epilogue.
// One wave per 16-row tile.
// ---------------------------------------------------------------------------
__global__ __launch_bounds__(256) void hp_gemm(const unsigned short* __restrict__ h,
                                               const unsigned short* __restrict__ wTk,
                                               const unsigned short* __restrict__ ak_src,
                                               const unsigned short* __restrict__ ak_trg,
                                               unsigned short* __restrict__ hp2,
                                               float* __restrict__ sb, float* __restrict__ tb)
{
    int wave = (blockIdx.x * 256 + threadIdx.x) >> 6;
    int lane = threadIdx.x & 63;
    if (wave >= NN / 16) return;
    int m0 = wave * 16;
    int mi = lane & 15, quad = lane >> 4;

    short8 a[4];
    const unsigned short* hrow = h + (size_t)(m0 + mi) * FIN + quad * 8;
#pragma unroll
    for (int kk = 0; kk < 4; kk++) a[kk] = *(const short8*)(hrow + kk * 32);

    float sp[4][4], tp[4][4];
#pragma unroll
    for (int r = 0; r < 4; r++)
#pragma unroll
        for (int q2 = 0; q2 < 4; q2++) { sp[r][q2] = 0.f; tp[r][q2] = 0.f; }

#pragma unroll
    for (int nt = 0; nt < 16; nt++) {
        int c = nt * 16 + mi;
        int hh = nt >> 2, fc = c & 63;
        floatx4 acc = {0.f, 0.f, 0.f, 0.f};
#pragma unroll
        for (int kk = 0; kk < 4; kk++) {
            short8 b = *(const short8*)(wTk + (size_t)((hh * 16 + kk * 4 + quad) * 64 + (nt & 3) * 16 + mi) * 8);
            acc = __builtin_amdgcn_mfma_f32_16x16x32_bf16(a[kk], b, acc, 0, 0, 0);
        }
        float asv = bf2f(ak_src[c]);
        float atv = bf2f(ak_trg[c]);
#pragma unroll
        for (int reg = 0; reg < 4; reg++) {
            float v = acc[reg];
            hp2[(size_t)(m0 + quad * 4 + reg) * 256 + fc * 4 + hh] = f2bf(v);
            sp[reg][hh] += v * asv;
            tp[reg][hh] += v * atv;
        }
    }
    // reduce over the 16 mi-lanes within each quad
#pragma unroll
    for (int off = 1; off < 16; off <<= 1)
#pragma unroll
        for (int r = 0; r < 4; r++)
#pragma unroll
            for (int q2 = 0; q2 < 4; q2++) {
                sp[r][q2] += __shfl_xor(sp[r][q2], off, 64);
                tp[r][q2] += __shfl_xor(tp[r][q2], off, 64);
            }
    // lane mi writes element (reg=mi>>2, h=mi&3)
    float sv = 0.f, tv = 0.f;
#pragma unroll
    for (int r = 0; r < 4; r++)
#pragma unroll
        for (int q2 = 0; q2 < 4; q2++) {
            bool sel = (mi == r * 4 + q2);
            sv = sel ? sp[r][q2] : sv;
            tv = sel ? tp[r][q2] : tv;
        }
    int rr = m0 + quad * 4 + (mi >> 2);
    sb[rr * 4 + (mi & 3)] = sv;
    tb[rr * 4 + (mi & 3)] = tv;
}

// ---------------------------------------------------------------------------
// passB2: wave per user node, CSR edges, register accumulate, one plain store.
// ---------------------------------------------------------------------------
__global__ __launch_bounds__(256) void passB2(const unsigned int* __restrict__ rowptr,
                                              const int* __restrict__ srcl,
                                              const float* __restrict__ sb,
                                              const float* __restrict__ tb,
                                              const unsigned short* __restrict__ hp2,
                                              float* __restrict__ ta)
{
    int n = blockIdx.x * 4 + (threadIdx.x >> 6);
    int f = threadIdx.x & 63;
    unsigned int beg = rowptr[n], end = rowptr[n + 1];
    float4 t4 = *(const float4*)(tb + (size_t)n * 4);
    float d0 = 0.f, d1 = 0.f, d2 = 0.f, d3 = 0.f;
    for (unsigned int p = beg; p < end; ++p) {
        int sn = srcl[p];
        float4 s4 = *(const float4*)(sb + (size_t)sn * 4);
        float v0 = s4.x + t4.x, v1 = s4.y + t4.y, v2 = s4.z + t4.z, v3 = s4.w + t4.w;
        v0 = (v0 >= 0.f) ? v0 : 0.2f * v0;  v1 = (v1 >= 0.f) ? v1 : 0.2f * v1;
        v2 = (v2 >= 0.f) ? v2 : 0.2f * v2;  v3 = (v3 >= 0.f) ? v3 : 0.2f * v3;
        d0 += __expf(v0); d1 += __expf(v1); d2 += __expf(v2); d3 += __expf(v3);
    }
    float i0 = 1.f / (d0 + 1e-16f), i1 = 1.f / (d1 + 1e-16f);
    float i2 = 1.f / (d2 + 1e-16f), i3 = 1.f / (d3 + 1e-16f);
    float acc = 0.f;
    for (unsigned int p = beg; p < end; ++p) {
        int sn = srcl[p];
        float4 s4 = *(const float4*)(sb + (size_t)sn * 4);
        float v0 = s4.x + t4.x, v1 = s4.y + t4.y, v2 = s4.z + t4.z, v3 = s4.w + t4.w;
        v0 = (v0 >= 0.f) ? v0 : 0.2f * v0;  v1 = (v1 >= 0.f) ? v1 : 0.2f * v1;
        v2 = (v2 >= 0.f) ? v2 : 0.2f * v2;  v3 = (v3 >= 0.f) ? v3 : 0.2f * v3;
        ushort4 hv = *(const ushort4*)(hp2 + (size_t)sn * 256 + f * 4);
        acc += __expf(v0) * i0 * bf2f(hv.x) + __expf(v1) * i1 * bf2f(hv.y)
             + __expf(v2) * i2 * bf2f(hv.z) + __expf(v3) * i3 * bf2f(hv.w);
    }
    ta[(size_t)n * 64 + f] = 0.25f * acc;
}

// ---------------------------------------------------------------------------
// C(Mx64 f32) = A(M x 32*nkk bf16, lda) @ BT (fragment layout, Npad=64)
// ---------------------------------------------------------------------------
__global__ __launch_bounds__(256) void gemm64T(const unsigned short* __restrict__ A, int lda, int nkk,
                                               const unsigned short* __restrict__ BT,
                                               float* __restrict__ C, int M)
{
    int wave = (blockIdx.x * 256 + threadIdx.x) >> 6;
    int lane = threadIdx.x & 63;
    int m0 = wave * 16;
    if (m0 >= M) return;
    int mi = lane & 15, quad = lane >> 4;
    floatx4 acc[4];
#pragma unroll
    for (int nt = 0; nt < 4; nt++) acc[nt] = (floatx4){0.f, 0.f, 0.f, 0.f};
    for (int kk = 0; kk < nkk; kk++) {
        short8 a = *(const short8*)(A + (size_t)(m0 + mi) * lda + kk * 32 + quad * 8);
#pragma unroll
        for (int nt = 0; nt < 4; nt++) {
            short8 b = *(const short8*)(BT + (size_t)((kk * 4 + quad) * 64 + nt * 16 + mi) * 8);
            acc[nt] = __builtin_amdgcn_mfma_f32_16x16x32_bf16(a, b, acc[nt], 0, 0, 0);
        }
    }
#pragma unroll
    for (int nt = 0; nt < 4; nt++)
#pragma unroll
        for (int reg = 0; reg < 4; reg++)
            C[(size_t)(m0 + quad * 4 + reg) * 64 + nt * 16 + mi] = acc[nt][reg];
}

// ---------------------------------------------------------------------------
// ret[:, 0:192] = bf16(ta)
// ---------------------------------------------------------------------------
__global__ __launch_bounds__(256) void cvt_ta(const float* __restrict__ ta, unsigned short* __restrict__ ret)
{
    int tid = blockIdx.x * 256 + threadIdx.x;   // NUSER*192
    int n = tid / 192;
    int c = tid - n * 192;
    int k = c >> 6, f = c & 63;
    ret[(size_t)n * 256 + c] = f2bf(ta[((size_t)k * NUSER + n) * 64 + f]);
}

// ---------------------------------------------------------------------------
// scores[n][k] = sum_f tanh( fw1[n][f] + (ta_k @ w2)[n][f] ) * m[f]
// ---------------------------------------------------------------------------
__global__ __launch_bounds__(256) void qscore_gemm(const unsigned short* __restrict__ retA,
                                                   const unsigned short* __restrict__ w2T,
                                                   const float* __restrict__ fw1,
                                                   const unsigned short* __restrict__ mvec,
                                                   float* __restrict__ scores, int M)
{
    int k = blockIdx.y;
    int wave = (blockIdx.x * 256 + threadIdx.x) >> 6;
    int lane = threadIdx.x & 63;
    int m0 = wave * 16;
    if (m0 >= M) return;
    int mi = lane & 15, quad = lane >> 4;
    const unsigned short* A = retA + k * 64;
    floatx4 acc[4];
#pragma unroll
    for (int nt = 0; nt < 4; nt++) acc[nt] = (floatx4){0.f, 0.f, 0.f, 0.f};
#pragma unroll
    for (int kk = 0; kk < 2; kk++) {
        short8 a = *(const short8*)(A + (size_t)(m0 + mi) * 256 + kk * 32 + quad * 8);
#pragma unroll
        for (int nt = 0; nt < 4; nt++) {
            short8 b = *(const short8*)(w2T + (size_t)((kk * 4 + quad) * 64 + nt * 16 + mi) * 8);
            acc[nt] = __builtin_amdgcn_mfma_f32_16x16x32_bf16(a, b, acc[nt], 0, 0, 0);
        }
    }
    float part[4] = {0.f, 0.f, 0.f, 0.f};
#pragma unroll
    for (int nt = 0; nt < 4; nt++) {
        int col = nt * 16 + mi;
        float mval = bf2f(mvec[col]);
#pragma unroll
        for (int reg = 0; reg < 4; reg++) {
            int rowg = m0 + quad * 4 + reg;
            float x = acc[nt][reg] + fw1[(size_t)rowg * 64 + col];
            float q = 1.f - 2.f / (1.f + __expf(2.f * x));   // tanh, NaN-free
            part[reg] += q * mval;
        }
    }
#pragma unroll
    for (int off = 1; off < 16; off <<= 1)
#pragma unroll
        for (int reg = 0; reg < 4; reg++) part[reg] += __shfl_xor(part[reg], off, 64);
    if (mi == 0) {
#pragma unroll
        for (int reg = 0; reg < 4; reg++)
            scores[(size_t)(m0 + quad * 4 + reg) * 3 + k] = part[reg];
    }
}

// ---------------------------------------------------------------------------
// beta = softmax(scores); ret[:,192:256] = bf16(sum_k beta_k * ta_k)
// ---------------------------------------------------------------------------
__global__ __launch_bounds__(256) void fuse_kernel(const float* __restrict__ scores,
                                                   const float* __restrict__ ta,
                                                   unsigned short* __restrict__ ret)
{
    int n = blockIdx.x * 4 + (threadIdx.x >> 6);
    int f = threadIdx.x & 63;
    float s0 = scores[n * 3 + 0], s1 = scores[n * 3 + 1], s2 = scores[n * 3 + 2];
    float mx = fmaxf(s0, fmaxf(s1, s2));
    float e0 = __expf(s0 - mx), e1 = __expf(s1 - mx), e2 = __expf(s2 - mx);
    float inv = 1.f / (e0 + e1 + e2);
    float fu = (e0 * ta[((size_t)0 * NUSER + n) * 64 + f] +
                e1 * ta[((size_t)1 * NUSER + n) * 64 + f] +
                e2 * ta[((size_t)2 * NUSER + n) * 64 + f]) * inv;
    ret[(size_t)n * 256 + 192 + f] = f2bf(fu);
}

// ---------------------------------------------------------------------------
// logits = ret(M x 256) @ fcwT(+bias) -> f32
// ---------------------------------------------------------------------------
__global__ __launch_bounds__(256) void fc_gemm(const unsigned short* __restrict__ A,
                                               const unsigned short* __restrict__ fcwT,
                                               const unsigned short* __restrict__ bias,
                                               float* __restrict__ C, int M)
{
    int wave = (blockIdx.x * 256 + threadIdx.x) >> 6;
    int lane = threadIdx.x & 63;
    int m0 = wave * 16;
    if (m0 >= M) return;
    int mi = lane & 15, quad = lane >> 4;
    floatx4 acc[3];
#pragma unroll
    for (int nt = 0; nt < 3; nt++) acc[nt] = (floatx4){0.f, 0.f, 0.f, 0.f};
#pragma unroll
    for (int kk = 0; kk < 8; kk++) {
        short8 a = *(const short8*)(A + (size_t)(m0 + mi) * 256 + kk * 32 + quad * 8);
#pragma unroll
        for (int nt = 0; nt < 3; nt++) {
            int col = nt * 16 + mi;
            short8 b = *(const short8*)(fcwT + (size_t)((kk * 4 + quad) * 48 + col) * 8);
            acc[nt] = __builtin_amdgcn_mfma_f32_16x16x32_bf16(a, b, acc[nt], 0, 0, 0);
        }
    }
#pragma unroll
    for (int nt = 0; nt < 3; nt++) {
        int col = nt * 16 + mi;
        if (col < NCLS) {
            float bv = bf2f(bias[col]);
#pragma unroll
            for (int reg = 0; reg < 4; reg++)
                C[(size_t)(m0 + quad * 4 + reg) * NCLS + col] = acc[nt][reg] + bv;
        }
    }
}

// ---------------------------------------------------------------------------
// out = log_softmax(logits); dtype per flag.
// ---------------------------------------------------------------------------
__global__ __launch_bounds__(256) void lsm_kernel(const float* __restrict__ logits,
                                                  const int* __restrict__ flagp,
                                                  void* __restrict__ out)
{
    int n = blockIdx.x * 4 + (threadIdx.x >> 6);
    int lane = threadIdx.x & 63;
    float v = (lane < NCLS) ? logits[(size_t)n * NCLS + lane] : -3.4e38f;
    float mx = v;
#pragma unroll
    for (int off = 32; off; off >>= 1) mx = fmaxf(mx, __shfl_xor(mx, off, 64));
    float ex = (lane < NCLS) ? __expf(v - mx) : 0.f;
    float sm = ex;
#pragma unroll
    for (int off = 32; off; off >>= 1) sm += __shfl_xor(sm, off, 64);
    float ls = v - mx - logf(sm);
    if (lane < NCLS) {
        size_t idx = (size_t)n * NCLS + lane;
        if (*flagp) ((float*)out)[idx] = ls;
        else        ((unsigned short*)out)[idx] = f2bf(ls);
    }
}

extern "C" void kernel_launch(void* const* d_in, const int* in_sizes, int n_in,
                              void* d_out, int out_size, void* d_ws, size_t ws_size,
                              hipStream_t stream)
{
    (void)in_sizes; (void)n_in; (void)out_size; (void)ws_size;
    const int* ei = (const int*)d_in[1];

    char* ws = (char*)d_ws;
    unsigned short* conv = (unsigned short*)ws;                 // 13,044,944 B
    unsigned short* hc   = conv + OFF_H;
    unsigned short* wc   = conv + OFF_W;
    unsigned short* asrc = conv + OFF_ASRC;
    unsigned short* atrg = conv + OFF_ATRG;
    unsigned short* w1c  = conv + OFF_W1;
    unsigned short* w2c  = conv + OFF_W2;
    unsigned short* mc   = conv + OFF_M;
    unsigned short* fcwc = conv + OFF_FCW;
    unsigned short* fcbc = conv + OFF_FCB;
    int* flag            = (int*)(ws + 13044944);
    float* ta            = (float*)(ws + 13045248);             // 30,720,000 B
    unsigned short* wT   = (unsigned short*)(ws + 43765248);    //    196,608 B
    unsigned short* w1T  = (unsigned short*)(ws + 43961856);    //     16,384 B
    unsigned short* w2T  = (unsigned short*)(ws + 43978240);    //      8,192 B
    unsigned short* fcwT = (unsigned short*)(ws + 43986432);    //     24,576 B
    unsigned int* cnt    = (unsigned int*)(ws + 44011008);      //    480,000 B
    unsigned int* rowptr = (unsigned int*)(ws + 44491008);      //    480,016 B
    int* srcl            = (int*)(ws + 44971024);               //  4,800,000 B
    float* sbuf          = (float*)(ws + 49771024);             //    800,000 B
    float* tbuf          = (float*)(ws + 50571024);             //    800,000 B
    unsigned short* hp2  = (unsigned short*)(ws + 51371024);    // 25,600,000 B
    // final-phase overlay of hp2 region
    float* scores        = (float*)(ws + 51371024);             //    480,000 B
    float* logits        = (float*)(ws + 51851024);             //  6,400,000 B
    unsigned short* ret  = (unsigned short*)(ws + 58251024);    // 20,480,000 B
    float* fw1           = (float*)(ws + 78731024);             // 10,240,000 B -> 88,971,024

    detect_kernel<<<1, 256, 0, stream>>>((const unsigned short*)d_in[0], flag);
    conv_kernel<<<(CONV_TOT + 255) / 256, 256, 0, stream>>>(
        d_in[0], d_in[2], d_in[3], d_in[4], d_in[5], d_in[6], d_in[7], d_in[8], d_in[9],
        flag, conv);

    // weight repacks (depend only on conv)
    repack_w<<<48, 256, 0, stream>>>(wc, wT);
    repack_small<<<12, 256, 0, stream>>>(w1c, w2c, fcwc, w1T, w2T, fcwT);

    // CSR sort of all 3 kinds (depends only on edge_index)
    hipMemsetAsync(cnt, 0, (size_t)KKIND * NUSER * 4, stream);
    hist3<<<dim3(1563, 3), 256, 0, stream>>>(ei, cnt);
    scan3<<<3, 1024, 0, stream>>>(cnt, rowptr);
    hipMemsetAsync(cnt, 0, (size_t)KKIND * NUSER * 4, stream);
    scatter3<<<dim3(1563, 3), 256, 0, stream>>>(ei, rowptr, cnt, srcl);

    for (int k = 0; k < KKIND; k++) {
        hp_gemm<<<782, 256, 0, stream>>>(hc, wT + (size_t)k * 32768,
                                         asrc + k * HHEAD * FOUT, atrg + k * HHEAD * FOUT,
                                         hp2, sbuf, tbuf);
        passB2<<<NUSER / 4, 256, 0, stream>>>(rowptr + (size_t)k * (NUSER + 1),
                                              srcl + (size_t)k * EE,
                                              sbuf, tbuf, hp2,
                                              ta + (size_t)k * NUSER * FOUT);
    }

    gemm64T<<<625, 256, 0, stream>>>(hc, FIN, 4, w1T, fw1, NUSER);
    cvt_ta<<<NUSER * 192 / 256, 256, 0, stream>>>(ta, ret);
    qscore_gemm<<<dim3(625, 3), 256, 0, stream>>>(ret, w2T, fw1, mc, scores, NUSER);
    fuse_kernel<<<NUSER / 4, 256, 0, stream>>>(scores, ta, ret);
    fc_gemm<<<625, 256, 0, stream>>>(ret, fcwT, fcbc, logits, NUSER);
    lsm_kernel<<<NUSER / 4, 256, 0, stream>>>(logits, flag, d_out);
}

// Round 4
// 489.855 us; speedup vs baseline: 1.3346x; 1.3076x over previous
//
#include <hip/hip_runtime.h>
#include <hip/hip_bf16.h>

#define NN    50000
#define NUSER 40000
#define EE    400000
#define KKIND 3
#define HHEAD 4
#define FIN   128
#define FOUT  64
#define NCLS  40

typedef __attribute__((ext_vector_type(8))) short short8;
typedef __attribute__((ext_vector_type(4))) float floatx4;

__device__ __forceinline__ float bf2f(unsigned short u) {
    unsigned int v = ((unsigned int)u) << 16;
    return __uint_as_float(v);
}
__device__ __forceinline__ unsigned short f2bf(float f) {
    unsigned int u = __float_as_uint(f);
    unsigned int r = (u + 0x7FFFu + ((u >> 16) & 1u)) >> 16;  // RNE
    return (unsigned short)r;
}

// conv-region element offsets (u16 elements)
#define OFF_H    0
#define OFF_W    6400000
#define OFF_ASRC 6498304
#define OFF_ATRG 6499072
#define OFF_W1   6499840
#define OFF_W2   6508032
#define OFF_M    6512128
#define OFF_FCW  6512192
#define OFF_FCB  6522432
#define CONV_TOT 6522472

// ---------------------------------------------------------------------------
// dtype detect (f32 vs bf16 float inputs)
// ---------------------------------------------------------------------------
__global__ __launch_bounds__(256) void detect_kernel(const unsigned short* __restrict__ hraw,
                                                     int* __restrict__ flag)
{
    __shared__ int cnt;
    if (threadIdx.x == 0) cnt = 0;
    __syncthreads();
    int local = 0;
#pragma unroll
    for (int j = 0; j < 8; j++) {
        unsigned short u = hraw[threadIdx.x * 8 + j];
        int ex = (u >> 7) & 0xFF;
        if (ex >= 0x90) local++;
    }
    atomicAdd(&cnt, local);
    __syncthreads();
    if (threadIdx.x == 0) *flag = (cnt > 100) ? 1 : 0;
}

__global__ __launch_bounds__(256) void conv_kernel(const void* __restrict__ p0, const void* __restrict__ p2,
                                                   const void* __restrict__ p3, const void* __restrict__ p4,
                                                   const void* __restrict__ p5, const void* __restrict__ p6,
                                                   const void* __restrict__ p7, const void* __restrict__ p8,
                                                   const void* __restrict__ p9,
                                                   const int* __restrict__ flagp,
                                                   unsigned short* __restrict__ dst)
{
    int tid = blockIdx.x * 256 + threadIdx.x;
    if (tid >= CONV_TOT) return;
    const void* src; int li;
    if      (tid < OFF_W)    { src = p0; li = tid - OFF_H; }
    else if (tid < OFF_ASRC) { src = p2; li = tid - OFF_W; }
    else if (tid < OFF_ATRG) { src = p3; li = tid - OFF_ASRC; }
    else if (tid < OFF_W1)   { src = p4; li = tid - OFF_ATRG; }
    else if (tid < OFF_W2)   { src = p5; li = tid - OFF_W1; }
    else if (tid < OFF_M)    { src = p6; li = tid - OFF_W2; }
    else if (tid < OFF_FCW)  { src = p7; li = tid - OFF_M; }
    else if (tid < OFF_FCB)  { src = p8; li = tid - OFF_FCW; }
    else                     { src = p9; li = tid - OFF_FCB; }
    unsigned short v;
    if (*flagp) v = f2bf(((const float*)src)[li]);
    else        v = ((const unsigned short*)src)[li];
    dst[tid] = v;
}

// ---------------------------------------------------------------------------
// B-matrix repacks into MFMA fragment layout
// ---------------------------------------------------------------------------
__global__ __launch_bounds__(256) void repack_w(const unsigned short* __restrict__ w,
                                                unsigned short* __restrict__ wT)
{
    int tid = blockIdx.x * 256 + threadIdx.x;       // 3*4*16*64 = 12288
    if (tid >= 12288) return;
    int f = tid & 63, g = (tid >> 6) & 15, h = (tid >> 10) & 3, k = tid >> 12;
    const unsigned short* src = w + (size_t)(k * 4 + h) * 8192 + f;
    unsigned short* dst = wT + (size_t)tid * 8;
#pragma unroll
    for (int j = 0; j < 8; j++) dst[j] = src[(size_t)(g * 8 + j) * 64];
}

__global__ __launch_bounds__(256) void repack_small(const unsigned short* __restrict__ w1,
                                                    const unsigned short* __restrict__ w2,
                                                    const unsigned short* __restrict__ fcw,
                                                    unsigned short* __restrict__ w1T,
                                                    unsigned short* __restrict__ w2T,
                                                    unsigned short* __restrict__ fcwT)
{
    int tid = blockIdx.x * 256 + threadIdx.x;
    if (tid < 1024) {                                 // w1: g in [0,16), c in [0,64)
        int c = tid & 63, g = tid >> 6;
#pragma unroll
        for (int j = 0; j < 8; j++) w1T[(size_t)(g * 64 + c) * 8 + j] = w1[(size_t)(g * 8 + j) * 64 + c];
    } else if (tid < 1536) {                          // w2: g in [0,8)
        int t = tid - 1024; int c = t & 63, g = t >> 6;
#pragma unroll
        for (int j = 0; j < 8; j++) w2T[(size_t)(g * 64 + c) * 8 + j] = w2[(size_t)(g * 8 + j) * 64 + c];
    } else if (tid < 3072) {                          // fcw: g in [0,32), c in [0,48)
        int t = tid - 1536; int c = t % 48, g = t / 48;
#pragma unroll
        for (int j = 0; j < 8; j++)
            fcwT[(size_t)(g * 48 + c) * 8 + j] = (c < NCLS) ? fcw[(size_t)(g * 8 + j) * NCLS + c] : (unsigned short)0;
    }
}

// ---------------------------------------------------------------------------
// CSR sort of edges by target (targets < NUSER only), all 3 kinds
// ---------------------------------------------------------------------------
__global__ __launch_bounds__(256) void hist3(const int* __restrict__ ei, unsigned int* __restrict__ cnt)
{
    int e = blockIdx.x * 256 + threadIdx.x;
    int k = blockIdx.y;
    if (e >= EE) return;
    int tn = ei[(size_t)k * 2 * EE + EE + e];
    if (tn < NUSER) atomicAdd(&cnt[(size_t)k * NUSER + tn], 1u);
}

__global__ __launch_bounds__(1024) void scan3(const unsigned int* __restrict__ cnt,
                                              unsigned int* __restrict__ rowptr)
{
    int k = blockIdx.x;
    const unsigned int* c = cnt + (size_t)k * NUSER;
    unsigned int* rp = rowptr + (size_t)k * (NUSER + 1);
    int lane = threadIdx.x & 63, wid = threadIdx.x >> 6;
    const int CH = 40;
    int base = threadIdx.x * CH;
    unsigned int s = 0;
#pragma unroll 4
    for (int i = 0; i < CH; i++) { int idx = base + i; if (idx < NUSER) s += c[idx]; }
    unsigned int v = s;
#pragma unroll
    for (int off = 1; off < 64; off <<= 1) { unsigned int u = __shfl_up(v, off, 64); if (lane >= off) v += u; }
    __shared__ unsigned int wsum[16];
    if (lane == 63) wsum[wid] = v;
    __syncthreads();
    if (wid == 0) {
        unsigned int x = (lane < 16) ? wsum[lane] : 0u;
#pragma unroll
        for (int off = 1; off < 16; off <<= 1) { unsigned int u = __shfl_up(x, off, 64); if (lane >= off) x += u; }
        if (lane < 16) wsum[lane] = x;
    }
    __syncthreads();
    unsigned int run = (v - s) + (wid ? wsum[wid - 1] : 0u);
    for (int i = 0; i < CH; i++) {
        int idx = base + i;
        if (idx < NUSER) { rp[idx] = run; run += c[idx]; }
    }
    if (threadIdx.x == 1023) rp[NUSER] = wsum[15];
}

__global__ __launch_bounds__(256) void scatter3(const int* __restrict__ ei,
                                                const unsigned int* __restrict__ rowptr,
                                                unsigned int* __restrict__ off,
                                                int* __restrict__ srcl)
{
    int e = blockIdx.x * 256 + threadIdx.x;
    int k = blockIdx.y;
    if (e >= EE) return;
    const int* srcA = ei + (size_t)k * 2 * EE;
    int tn = srcA[EE + e];
    if (tn >= NUSER) return;
    unsigned int p = rowptr[(size_t)k * (NUSER + 1) + tn] + atomicAdd(&off[(size_t)k * NUSER + tn], 1u);
    srcl[(size_t)k * EE + p] = srcA[e];
}

// ---------------------------------------------------------------------------
// hp2 = h @ w[k] in layout [n][f][4heads] bf16, fused s/t epilogue.
// 8B coalesced stores (ushort4 packs the 4 heads of one f).
// ---------------------------------------------------------------------------
__global__ __launch_bounds__(256) void hp_gemm(const unsigned short* __restrict__ h,
                                               const unsigned short* __restrict__ wTk,
                                               const unsigned short* __restrict__ ak_src,
                                               const unsigned short* __restrict__ ak_trg,
                                               unsigned short* __restrict__ hp2,
                                               float* __restrict__ sb, float* __restrict__ tb)
{
    int wave = (blockIdx.x * 256 + threadIdx.x) >> 6;
    int lane = threadIdx.x & 63;
    if (wave >= NN / 16) return;
    int m0 = wave * 16;
    int mi = lane & 15, quad = lane >> 4;

    short8 a[4];
    const unsigned short* hrow = h + (size_t)(m0 + mi) * FIN + quad * 8;
#pragma unroll
    for (int kk = 0; kk < 4; kk++) a[kk] = *(const short8*)(hrow + kk * 32);

    float sp[4][4], tp[4][4];
#pragma unroll
    for (int r = 0; r < 4; r++)
#pragma unroll
        for (int q2 = 0; q2 < 4; q2++) { sp[r][q2] = 0.f; tp[r][q2] = 0.f; }

#pragma unroll
    for (int j = 0; j < 4; j++) {
        int fc = j * 16 + mi;
        floatx4 acc4[4];
#pragma unroll
        for (int hh = 0; hh < 4; hh++) {
            floatx4 acc = {0.f, 0.f, 0.f, 0.f};
#pragma unroll
            for (int kk = 0; kk < 4; kk++) {
                short8 b = *(const short8*)(wTk + (size_t)((hh * 16 + kk * 4 + quad) * 64 + fc) * 8);
                acc = __builtin_amdgcn_mfma_f32_16x16x32_bf16(a[kk], b, acc, 0, 0, 0);
            }
            acc4[hh] = acc;
            float asv = bf2f(ak_src[hh * 64 + fc]);
            float atv = bf2f(ak_trg[hh * 64 + fc]);
#pragma unroll
            for (int reg = 0; reg < 4; reg++) {
                sp[reg][hh] += acc[reg] * asv;
                tp[reg][hh] += acc[reg] * atv;
            }
        }
#pragma unroll
        for (int reg = 0; reg < 4; reg++) {
            ushort4 pk;
            pk.x = f2bf(acc4[0][reg]); pk.y = f2bf(acc4[1][reg]);
            pk.z = f2bf(acc4[2][reg]); pk.w = f2bf(acc4[3][reg]);
            int row = m0 + quad * 4 + reg;
            *(ushort4*)(hp2 + (size_t)row * 256 + fc * 4) = pk;
        }
    }
#pragma unroll
    for (int off = 1; off < 16; off <<= 1)
#pragma unroll
        for (int r = 0; r < 4; r++)
#pragma unroll
            for (int q2 = 0; q2 < 4; q2++) {
                sp[r][q2] += __shfl_xor(sp[r][q2], off, 64);
                tp[r][q2] += __shfl_xor(tp[r][q2], off, 64);
            }
    float sv = 0.f, tv = 0.f;
#pragma unroll
    for (int r = 0; r < 4; r++)
#pragma unroll
        for (int q2 = 0; q2 < 4; q2++) {
            bool sel = (mi == r * 4 + q2);
            sv = sel ? sp[r][q2] : sv;
            tv = sel ? tp[r][q2] : tv;
        }
    int rr = m0 + quad * 4 + (mi >> 2);
    sb[rr * 4 + (mi & 3)] = sv;
    tb[rr * 4 + (mi & 3)] = tv;
}

// ---------------------------------------------------------------------------
// passB3: wave per user node; single pass accumulating numerator AND
// denominator (division distributes out of the segment sum).  2 edges per
// wave (halves), 16B hp2 loads; writes ta f32 + ret bf16 slice directly.
// ---------------------------------------------------------------------------
__global__ __launch_bounds__(256) void passB3(const unsigned int* __restrict__ rowptr,
                                              const int* __restrict__ srcl,
                                              const float* __restrict__ sb,
                                              const float* __restrict__ tb,
                                              const unsigned short* __restrict__ hp2,
                                              float* __restrict__ ta,
                                              unsigned short* __restrict__ ret, int kslice)
{
    int n = blockIdx.x * 4 + (threadIdx.x >> 6);
    int lane = threadIdx.x & 63;
    int half = lane >> 5, l = lane & 31;
    unsigned int beg = rowptr[n], end = rowptr[n + 1];
    float4 t4 = *(const float4*)(tb + (size_t)n * 4);
    float n0 = 0.f, n1 = 0.f, n2 = 0.f, n3 = 0.f, n4 = 0.f, n5 = 0.f, n6 = 0.f, n7 = 0.f;
    float d0 = 0.f, d1 = 0.f, d2 = 0.f, d3 = 0.f;
    for (unsigned int p = beg + half; p < end; p += 2) {
        int sn = srcl[p];
        float4 s4 = *(const float4*)(sb + (size_t)sn * 4);
        short8 hv = *(const short8*)(hp2 + (size_t)sn * 256 + l * 8);
        float v0 = s4.x + t4.x, v1 = s4.y + t4.y, v2 = s4.z + t4.z, v3 = s4.w + t4.w;
        v0 = (v0 >= 0.f) ? v0 : 0.2f * v0;  v1 = (v1 >= 0.f) ? v1 : 0.2f * v1;
        v2 = (v2 >= 0.f) ? v2 : 0.2f * v2;  v3 = (v3 >= 0.f) ? v3 : 0.2f * v3;
        float e0 = __expf(v0), e1 = __expf(v1), e2 = __expf(v2), e3 = __expf(v3);
        d0 += e0; d1 += e1; d2 += e2; d3 += e3;
        n0 += e0 * bf2f((unsigned short)hv[0]); n1 += e1 * bf2f((unsigned short)hv[1]);
        n2 += e2 * bf2f((unsigned short)hv[2]); n3 += e3 * bf2f((unsigned short)hv[3]);
        n4 += e0 * bf2f((unsigned short)hv[4]); n5 += e1 * bf2f((unsigned short)hv[5]);
        n6 += e2 * bf2f((unsigned short)hv[6]); n7 += e3 * bf2f((unsigned short)hv[7]);
    }
    n0 += __shfl_xor(n0, 32, 64); n1 += __shfl_xor(n1, 32, 64);
    n2 += __shfl_xor(n2, 32, 64); n3 += __shfl_xor(n3, 32, 64);
    n4 += __shfl_xor(n4, 32, 64); n5 += __shfl_xor(n5, 32, 64);
    n6 += __shfl_xor(n6, 32, 64); n7 += __shfl_xor(n7, 32, 64);
    d0 += __shfl_xor(d0, 32, 64); d1 += __shfl_xor(d1, 32, 64);
    d2 += __shfl_xor(d2, 32, 64); d3 += __shfl_xor(d3, 32, 64);
    float i0 = 1.f / (d0 + 1e-16f), i1 = 1.f / (d1 + 1e-16f);
    float i2 = 1.f / (d2 + 1e-16f), i3 = 1.f / (d3 + 1e-16f);
    float r0 = 0.25f * (n0 * i0 + n1 * i1 + n2 * i2 + n3 * i3);
    float r1 = 0.25f * (n4 * i0 + n5 * i1 + n6 * i2 + n7 * i3);
    int f0 = l * 2;
    if (half == 0) {
        float2 st = {r0, r1};
        *(float2*)(ta + (size_t)n * 64 + f0) = st;
    } else {
        ushort2 sb2; sb2.x = f2bf(r0); sb2.y = f2bf(r1);
        *(ushort2*)(ret + (size_t)n * 256 + kslice * 64 + f0) = sb2;
    }
}

// ---------------------------------------------------------------------------
// qscore2: per 16-row tile, compute fw1 tile = h@w1 in-register, then for
// each k: q = tanh(fw1 + ta_k@w2), scores[n][k] = q . m
// ---------------------------------------------------------------------------
__global__ __launch_bounds__(256) void qscore2(const unsigned short* __restrict__ h,
                                               const unsigned short* __restrict__ w1T,
                                               const unsigned short* __restrict__ retA,
                                               const unsigned short* __restrict__ w2T,
                                               const unsigned short* __restrict__ mvec,
                                               float* __restrict__ scores, int M)
{
    int wave = (blockIdx.x * 256 + threadIdx.x) >> 6;
    int lane = threadIdx.x & 63;
    int m0 = wave * 16;
    if (m0 >= M) return;
    int mi = lane & 15, quad = lane >> 4;

    // fw1 tile
    floatx4 fw[4];
#pragma unroll
    for (int nt = 0; nt < 4; nt++) fw[nt] = (floatx4){0.f, 0.f, 0.f, 0.f};
#pragma unroll
    for (int kk = 0; kk < 4; kk++) {
        short8 a = *(const short8*)(h + (size_t)(m0 + mi) * FIN + kk * 32 + quad * 8);
#pragma unroll
        for (int nt = 0; nt < 4; nt++) {
            short8 b = *(const short8*)(w1T + (size_t)((kk * 4 + quad) * 64 + nt * 16 + mi) * 8);
            fw[nt] = __builtin_amdgcn_mfma_f32_16x16x32_bf16(a, b, fw[nt], 0, 0, 0);
        }
    }

    for (int k = 0; k < KKIND; k++) {
        floatx4 acc[4];
#pragma unroll
        for (int nt = 0; nt < 4; nt++) acc[nt] = (floatx4){0.f, 0.f, 0.f, 0.f};
#pragma unroll
        for (int kk = 0; kk < 2; kk++) {
            short8 a = *(const short8*)(retA + (size_t)(m0 + mi) * 256 + k * 64 + kk * 32 + quad * 8);
#pragma unroll
            for (int nt = 0; nt < 4; nt++) {
                short8 b = *(const short8*)(w2T + (size_t)((kk * 4 + quad) * 64 + nt * 16 + mi) * 8);
                acc[nt] = __builtin_amdgcn_mfma_f32_16x16x32_bf16(a, b, acc[nt], 0, 0, 0);
            }
        }
        float part[4] = {0.f, 0.f, 0.f, 0.f};
#pragma unroll
        for (int nt = 0; nt < 4; nt++) {
            int col = nt * 16 + mi;
            float mval = bf2f(mvec[col]);
#pragma unroll
            for (int reg = 0; reg < 4; reg++) {
                float x = acc[nt][reg] + fw[nt][reg];
                float q = 1.f - 2.f / (1.f + __expf(2.f * x));   // tanh, NaN-free
                part[reg] += q * mval;
            }
        }
#pragma unroll
        for (int off = 1; off < 16; off <<= 1)
#pragma unroll
            for (int reg = 0; reg < 4; reg++) part[reg] += __shfl_xor(part[reg], off, 64);
        if (mi == 0) {
#pragma unroll
            for (int reg = 0; reg < 4; reg++)
                scores[(size_t)(m0 + quad * 4 + reg) * 3 + k] = part[reg];
        }
    }
}

// ---------------------------------------------------------------------------
// beta = softmax(scores); ret[:,192:256] = bf16(sum_k beta_k * ta_k)
// ---------------------------------------------------------------------------
__global__ __launch_bounds__(256) void fuse_kernel(const float* __restrict__ scores,
                                                   const float* __restrict__ ta,
                                                   unsigned short* __restrict__ ret)
{
    int n = blockIdx.x * 4 + (threadIdx.x >> 6);
    int f = threadIdx.x & 63;
    float s0 = scores[n * 3 + 0], s1 = scores[n * 3 + 1], s2 = scores[n * 3 + 2];
    float mx = fmaxf(s0, fmaxf(s1, s2));
    float e0 = __expf(s0 - mx), e1 = __expf(s1 - mx), e2 = __expf(s2 - mx);
    float inv = 1.f / (e0 + e1 + e2);
    float fu = (e0 * ta[((size_t)0 * NUSER + n) * 64 + f] +
                e1 * ta[((size_t)1 * NUSER + n) * 64 + f] +
                e2 * ta[((size_t)2 * NUSER + n) * 64 + f]) * inv;
    ret[(size_t)n * 256 + 192 + f] = f2bf(fu);
}

// ---------------------------------------------------------------------------
// logits = ret(M x 256) @ fcwT + bias, fused log_softmax -> out (dtype per flag)
// ---------------------------------------------------------------------------
__global__ __launch_bounds__(256) void fc_lsm(const unsigned short* __restrict__ A,
                                              const unsigned short* __restrict__ fcwT,
                                              const unsigned short* __restrict__ bias,
                                              const int* __restrict__ flagp,
                                              void* __restrict__ out, int M)
{
    int wave = (blockIdx.x * 256 + threadIdx.x) >> 6;
    int lane = threadIdx.x & 63;
    int m0 = wave * 16;
    if (m0 >= M) return;
    int mi = lane & 15, quad = lane >> 4;
    floatx4 acc[3];
#pragma unroll
    for (int nt = 0; nt < 3; nt++) acc[nt] = (floatx4){0.f, 0.f, 0.f, 0.f};
#pragma unroll
    for (int kk = 0; kk < 8; kk++) {
        short8 a = *(const short8*)(A + (size_t)(m0 + mi) * 256 + kk * 32 + quad * 8);
#pragma unroll
        for (int nt = 0; nt < 3; nt++) {
            short8 b = *(const short8*)(fcwT + (size_t)((kk * 4 + quad) * 48 + nt * 16 + mi) * 8);
            acc[nt] = __builtin_amdgcn_mfma_f32_16x16x32_bf16(a, b, acc[nt], 0, 0, 0);
        }
    }
    int fl = *flagp;
    float bv[3]; bool ok[3];
#pragma unroll
    for (int nt = 0; nt < 3; nt++) {
        int col = nt * 16 + mi;
        ok[nt] = (col < NCLS);
        bv[nt] = ok[nt] ? bf2f(bias[col]) : 0.f;
    }
#pragma unroll
    for (int reg = 0; reg < 4; reg++) {
        float v[3];
#pragma unroll
        for (int nt = 0; nt < 3; nt++)
            v[nt] = ok[nt] ? (acc[nt][reg] + bv[nt]) : -3.4e38f;
        float mx = fmaxf(fmaxf(v[0], v[1]), v[2]);
#pragma unroll
        for (int off = 1; off < 16; off <<= 1) mx = fmaxf(mx, __shfl_xor(mx, off, 64));
        float s = 0.f;
#pragma unroll
        for (int nt = 0; nt < 3; nt++) s += ok[nt] ? __expf(v[nt] - mx) : 0.f;
#pragma unroll
        for (int off = 1; off < 16; off <<= 1) s += __shfl_xor(s, off, 64);
        float lse = mx + __logf(s);
        int row = m0 + quad * 4 + reg;
#pragma unroll
        for (int nt = 0; nt < 3; nt++) {
            int col = nt * 16 + mi;
            if (col < NCLS) {
                float ls = v[nt] - lse;
                size_t idx = (size_t)row * NCLS + col;
                if (fl) ((float*)out)[idx] = ls;
                else    ((unsigned short*)out)[idx] = f2bf(ls);
            }
        }
    }
}

extern "C" void kernel_launch(void* const* d_in, const int* in_sizes, int n_in,
                              void* d_out, int out_size, void* d_ws, size_t ws_size,
                              hipStream_t stream)
{
    (void)in_sizes; (void)n_in; (void)out_size; (void)ws_size;
    const int* ei = (const int*)d_in[1];

    char* ws = (char*)d_ws;
    unsigned short* conv = (unsigned short*)ws;                 // 13,044,944 B
    unsigned short* hc   = conv + OFF_H;
    unsigned short* wc   = conv + OFF_W;
    unsigned short* asrc = conv + OFF_ASRC;
    unsigned short* atrg = conv + OFF_ATRG;
    unsigned short* w1c  = conv + OFF_W1;
    unsigned short* w2c  = conv + OFF_W2;
    unsigned short* mc   = conv + OFF_M;
    unsigned short* fcwc = conv + OFF_FCW;
    unsigned short* fcbc = conv + OFF_FCB;
    int* flag            = (int*)(ws + 13044944);
    float* ta            = (float*)(ws + 13045248);             // 30,720,000 B
    unsigned short* wT   = (unsigned short*)(ws + 43765248);    //    196,608 B
    unsigned short* w1T  = (unsigned short*)(ws + 43961856);    //     16,384 B
    unsigned short* w2T  = (unsigned short*)(ws + 43978240);    //      8,192 B
    unsigned short* fcwT = (unsigned short*)(ws + 43986432);    //     24,576 B
    unsigned int* cnt    = (unsigned int*)(ws + 44011008);      //    480,000 B
    unsigned int* rowptr = (unsigned int*)(ws + 44491008);      //    480,016 B
    int* srcl            = (int*)(ws + 44971024);               //  4,800,000 B
    float* sbuf          = (float*)(ws + 49771024);             //    800,000 B
    float* tbuf          = (float*)(ws + 50571024);             //    800,000 B
    unsigned short* hp2  = (unsigned short*)(ws + 51371024);    // 25,600,000 B -> 76,971,024
    float* scores        = (float*)(ws + 51371024);             // overlay (post-loop)
    unsigned short* ret  = (unsigned short*)(ws + 76971024);    // 20,480,000 B -> 97,451,024

    detect_kernel<<<1, 256, 0, stream>>>((const unsigned short*)d_in[0], flag);
    conv_kernel<<<(CONV_TOT + 255) / 256, 256, 0, stream>>>(
        d_in[0], d_in[2], d_in[3], d_in[4], d_in[5], d_in[6], d_in[7], d_in[8], d_in[9],
        flag, conv);

    repack_w<<<48, 256, 0, stream>>>(wc, wT);
    repack_small<<<12, 256, 0, stream>>>(w1c, w2c, fcwc, w1T, w2T, fcwT);

    hipMemsetAsync(cnt, 0, (size_t)KKIND * NUSER * 4, stream);
    hist3<<<dim3(1563, 3), 256, 0, stream>>>(ei, cnt);
    scan3<<<3, 1024, 0, stream>>>(cnt, rowptr);
    hipMemsetAsync(cnt, 0, (size_t)KKIND * NUSER * 4, stream);
    scatter3<<<dim3(1563, 3), 256, 0, stream>>>(ei, rowptr, cnt, srcl);

    for (int k = 0; k < KKIND; k++) {
        hp_gemm<<<782, 256, 0, stream>>>(hc, wT + (size_t)k * 32768,
                                         asrc + k * HHEAD * FOUT, atrg + k * HHEAD * FOUT,
                                         hp2, sbuf, tbuf);
        passB3<<<NUSER / 4, 256, 0, stream>>>(rowptr + (size_t)k * (NUSER + 1),
                                              srcl + (size_t)k * EE,
                                              sbuf, tbuf, hp2,
                                              ta + (size_t)k * NUSER * FOUT, ret, k);
    }

    qscore2<<<625, 256, 0, stream>>>(hc, w1T, ret, w2T, mc, scores, NUSER);
    fuse_kernel<<<NUSER / 4, 256, 0, stream>>>(scores, ta, ret);
    fc_lsm<<<625, 256, 0, stream>>>(ret, fcwT, fcbc, flag, d_out, NUSER);
}

// Round 5
// 424.247 us; speedup vs baseline: 1.5409x; 1.1546x over previous
//
#include <hip/hip_runtime.h>
#include <hip/hip_bf16.h>

#define NN    50000
#define NUSER 40000
#define EE    400000
#define KKIND 3
#define HHEAD 4
#define FIN   128
#define FOUT  64
#define NCLS  40

typedef __attribute__((ext_vector_type(8))) short short8;
typedef __attribute__((ext_vector_type(4))) float floatx4;

__device__ __forceinline__ float bf2f(unsigned short u) {
    unsigned int v = ((unsigned int)u) << 16;
    return __uint_as_float(v);
}
__device__ __forceinline__ unsigned short f2bf(float f) {
    unsigned int u = __float_as_uint(f);
    unsigned int r = (u + 0x7FFFu + ((u >> 16) & 1u)) >> 16;  // RNE
    return (unsigned short)r;
}

// conv-region element offsets (u16 elements) — all multiples of 8
#define OFF_H    0
#define OFF_W    6400000
#define OFF_ASRC 6498304
#define OFF_ATRG 6499072
#define OFF_W1   6499840
#define OFF_W2   6508032
#define OFF_M    6512128
#define OFF_FCW  6512192
#define OFF_FCB  6522432
#define CONV_TOT 6522472

// ---------------------------------------------------------------------------
// dtype detect (f32 vs bf16 float inputs)
// ---------------------------------------------------------------------------
__global__ __launch_bounds__(256) void detect_kernel(const unsigned short* __restrict__ hraw,
                                                     int* __restrict__ flag)
{
    __shared__ int cnt;
    if (threadIdx.x == 0) cnt = 0;
    __syncthreads();
    int local = 0;
#pragma unroll
    for (int j = 0; j < 8; j++) {
        unsigned short u = hraw[threadIdx.x * 8 + j];
        int ex = (u >> 7) & 0xFF;
        if (ex >= 0x90) local++;
    }
    atomicAdd(&cnt, local);
    __syncthreads();
    if (threadIdx.x == 0) *flag = (cnt > 100) ? 1 : 0;
}

// 8 u16 elements per thread; segment boundaries all %8==0
__global__ __launch_bounds__(256) void conv_kernel(const void* __restrict__ p0, const void* __restrict__ p2,
                                                   const void* __restrict__ p3, const void* __restrict__ p4,
                                                   const void* __restrict__ p5, const void* __restrict__ p6,
                                                   const void* __restrict__ p7, const void* __restrict__ p8,
                                                   const void* __restrict__ p9,
                                                   const int* __restrict__ flagp,
                                                   unsigned short* __restrict__ dst)
{
    int tid = (blockIdx.x * 256 + threadIdx.x) * 8;
    if (tid >= CONV_TOT) return;
    const void* src; int li;
    if      (tid < OFF_W)    { src = p0; li = tid - OFF_H; }
    else if (tid < OFF_ASRC) { src = p2; li = tid - OFF_W; }
    else if (tid < OFF_ATRG) { src = p3; li = tid - OFF_ASRC; }
    else if (tid < OFF_W1)   { src = p4; li = tid - OFF_ATRG; }
    else if (tid < OFF_W2)   { src = p5; li = tid - OFF_W1; }
    else if (tid < OFF_M)    { src = p6; li = tid - OFF_W2; }
    else if (tid < OFF_FCW)  { src = p7; li = tid - OFF_M; }
    else if (tid < OFF_FCB)  { src = p8; li = tid - OFF_FCW; }
    else                     { src = p9; li = tid - OFF_FCB; }
    if (*flagp) {
        const float* fp = (const float*)src + li;
        float4 x = *(const float4*)fp;
        float4 y = *(const float4*)(fp + 4);
        uint4 o;
        o.x = (unsigned int)f2bf(x.x) | ((unsigned int)f2bf(x.y) << 16);
        o.y = (unsigned int)f2bf(x.z) | ((unsigned int)f2bf(x.w) << 16);
        o.z = (unsigned int)f2bf(y.x) | ((unsigned int)f2bf(y.y) << 16);
        o.w = (unsigned int)f2bf(y.z) | ((unsigned int)f2bf(y.w) << 16);
        *(uint4*)(dst + tid) = o;
    } else {
        *(uint4*)(dst + tid) = *(const uint4*)((const unsigned short*)src + li);
    }
}

// ---------------------------------------------------------------------------
// B-matrix repacks into MFMA fragment layout
// ---------------------------------------------------------------------------
__global__ __launch_bounds__(256) void repack_w(const unsigned short* __restrict__ w,
                                                unsigned short* __restrict__ wT)
{
    int tid = blockIdx.x * 256 + threadIdx.x;       // 3*4*16*64 = 12288
    if (tid >= 12288) return;
    int f = tid & 63, g = (tid >> 6) & 15, h = (tid >> 10) & 3, k = tid >> 12;
    const unsigned short* src = w + (size_t)(k * 4 + h) * 8192 + f;
    unsigned short* dst = wT + (size_t)tid * 8;
#pragma unroll
    for (int j = 0; j < 8; j++) dst[j] = src[(size_t)(g * 8 + j) * 64];
}

__global__ __launch_bounds__(256) void repack_small(const unsigned short* __restrict__ w1,
                                                    const unsigned short* __restrict__ w2,
                                                    const unsigned short* __restrict__ fcw,
                                                    unsigned short* __restrict__ w1T,
                                                    unsigned short* __restrict__ w2T,
                                                    unsigned short* __restrict__ fcwT)
{
    int tid = blockIdx.x * 256 + threadIdx.x;
    if (tid < 1024) {                                 // w1: g in [0,16), c in [0,64)
        int c = tid & 63, g = tid >> 6;
#pragma unroll
        for (int j = 0; j < 8; j++) w1T[(size_t)(g * 64 + c) * 8 + j] = w1[(size_t)(g * 8 + j) * 64 + c];
    } else if (tid < 1536) {                          // w2: g in [0,8)
        int t = tid - 1024; int c = t & 63, g = t >> 6;
#pragma unroll
        for (int j = 0; j < 8; j++) w2T[(size_t)(g * 64 + c) * 8 + j] = w2[(size_t)(g * 8 + j) * 64 + c];
    } else if (tid < 3072) {                          // fcw: g in [0,32), c in [0,48)
        int t = tid - 1536; int c = t % 48, g = t / 48;
#pragma unroll
        for (int j = 0; j < 8; j++)
            fcwT[(size_t)(g * 48 + c) * 8 + j] = (c < NCLS) ? fcw[(size_t)(g * 8 + j) * NCLS + c] : (unsigned short)0;
    }
}

// ---------------------------------------------------------------------------
// CSR sort of edges by target (targets < NUSER only), all 3 kinds
// ---------------------------------------------------------------------------
__global__ __launch_bounds__(256) void hist3(const int* __restrict__ ei, unsigned int* __restrict__ cnt)
{
    int e = blockIdx.x * 256 + threadIdx.x;
    int k = blockIdx.y;
    if (e >= EE) return;
    int tn = ei[(size_t)k * 2 * EE + EE + e];
    if (tn < NUSER) atomicAdd(&cnt[(size_t)k * NUSER + tn], 1u);
}

// 3-phase multi-block exclusive scan: A = block sums, B = scan 20 partials
// per kind (1 wave each), C = apply offsets and write rowptr.
#define SCB 20          // blocks per kind, 2048 elements each
__global__ __launch_bounds__(256) void scanA(const unsigned int* __restrict__ cnt,
                                             unsigned int* __restrict__ partials)
{
    int k = blockIdx.y, b = blockIdx.x;
    const unsigned int* c = cnt + (size_t)k * NUSER;
    int base = b * 2048 + threadIdx.x * 8;
    unsigned int s = 0;
#pragma unroll
    for (int j = 0; j < 8; j++) { int idx = base + j; if (idx < NUSER) s += c[idx]; }
#pragma unroll
    for (int off = 1; off < 64; off <<= 1) s += __shfl_xor(s, off, 64);
    __shared__ unsigned int wsum[4];
    int lane = threadIdx.x & 63, wid = threadIdx.x >> 6;
    if (lane == 0) wsum[wid] = s;
    __syncthreads();
    if (threadIdx.x == 0) partials[k * SCB + b] = wsum[0] + wsum[1] + wsum[2] + wsum[3];
}

__global__ __launch_bounds__(256) void scanB(unsigned int* __restrict__ partials,
                                             unsigned int* __restrict__ rowptr)
{
    int wid = threadIdx.x >> 6, lane = threadIdx.x & 63;
    if (wid >= KKIND) return;
    unsigned int v = (lane < SCB) ? partials[wid * SCB + lane] : 0u;
    unsigned int inc = v;
#pragma unroll
    for (int off = 1; off < 32; off <<= 1) {
        unsigned int u = __shfl_up(inc, off, 64);
        if (lane >= off) inc += u;
    }
    if (lane < SCB) partials[wid * SCB + lane] = inc - v;      // exclusive
    if (lane == SCB - 1) rowptr[(size_t)wid * (NUSER + 1) + NUSER] = inc;  // total
}

__global__ __launch_bounds__(256) void scanC(const unsigned int* __restrict__ cnt,
                                             const unsigned int* __restrict__ partials,
                                             unsigned int* __restrict__ rowptr)
{
    int k = blockIdx.y, b = blockIdx.x;
    const unsigned int* c = cnt + (size_t)k * NUSER;
    unsigned int* rp = rowptr + (size_t)k * (NUSER + 1);
    int lane = threadIdx.x & 63, wid = threadIdx.x >> 6;
    int base = b * 2048 + threadIdx.x * 8;
    unsigned int vals[8]; unsigned int s = 0;
#pragma unroll
    for (int j = 0; j < 8; j++) { int idx = base + j; vals[j] = (idx < NUSER) ? c[idx] : 0u; s += vals[j]; }
    unsigned int inc = s;
#pragma unroll
    for (int off = 1; off < 64; off <<= 1) {
        unsigned int u = __shfl_up(inc, off, 64);
        if (lane >= off) inc += u;
    }
    __shared__ unsigned int wsum[4];
    if (lane == 63) wsum[wid] = inc;
    __syncthreads();
    unsigned int woff = 0;
    for (int i = 0; i < wid; i++) woff += wsum[i];
    unsigned int run = partials[k * SCB + b] + woff + (inc - s);
#pragma unroll
    for (int j = 0; j < 8; j++) {
        int idx = base + j;
        if (idx < NUSER) { rp[idx] = run; run += vals[j]; }
    }
}

__global__ __launch_bounds__(256) void scatter3(const int* __restrict__ ei,
                                                const unsigned int* __restrict__ rowptr,
                                                unsigned int* __restrict__ off,
                                                int* __restrict__ srcl)
{
    int e = blockIdx.x * 256 + threadIdx.x;
    int k = blockIdx.y;
    if (e >= EE) return;
    const int* srcA = ei + (size_t)k * 2 * EE;
    int tn = srcA[EE + e];
    if (tn >= NUSER) return;
    unsigned int p = rowptr[(size_t)k * (NUSER + 1) + tn] + atomicAdd(&off[(size_t)k * NUSER + tn], 1u);
    srcl[(size_t)k * EE + p] = srcA[e];
}

// ---------------------------------------------------------------------------
// hp2 = h @ w[k] in layout [n][f][4heads] bf16, fused s/t epilogue.
// ---------------------------------------------------------------------------
__global__ __launch_bounds__(256) void hp_gemm(const unsigned short* __restrict__ h,
                                               const unsigned short* __restrict__ wTk,
                                               const unsigned short* __restrict__ ak_src,
                                               const unsigned short* __restrict__ ak_trg,
                                               unsigned short* __restrict__ hp2,
                                               float* __restrict__ sb, float* __restrict__ tb)
{
    int wave = (blockIdx.x * 256 + threadIdx.x) >> 6;
    int lane = threadIdx.x & 63;
    if (wave >= NN / 16) return;
    int m0 = wave * 16;
    int mi = lane & 15, quad = lane >> 4;

    short8 a[4];
    const unsigned short* hrow = h + (size_t)(m0 + mi) * FIN + quad * 8;
#pragma unroll
    for (int kk = 0; kk < 4; kk++) a[kk] = *(const short8*)(hrow + kk * 32);

    float sp[4][4], tp[4][4];
#pragma unroll
    for (int r = 0; r < 4; r++)
#pragma unroll
        for (int q2 = 0; q2 < 4; q2++) { sp[r][q2] = 0.f; tp[r][q2] = 0.f; }

#pragma unroll
    for (int j = 0; j < 4; j++) {
        int fc = j * 16 + mi;
        floatx4 acc4[4];
#pragma unroll
        for (int hh = 0; hh < 4; hh++) {
            floatx4 acc = {0.f, 0.f, 0.f, 0.f};
#pragma unroll
            for (int kk = 0; kk < 4; kk++) {
                short8 b = *(const short8*)(wTk + (size_t)((hh * 16 + kk * 4 + quad) * 64 + fc) * 8);
                acc = __builtin_amdgcn_mfma_f32_16x16x32_bf16(a[kk], b, acc, 0, 0, 0);
            }
            acc4[hh] = acc;
            float asv = bf2f(ak_src[hh * 64 + fc]);
            float atv = bf2f(ak_trg[hh * 64 + fc]);
#pragma unroll
            for (int reg = 0; reg < 4; reg++) {
                sp[reg][hh] += acc[reg] * asv;
                tp[reg][hh] += acc[reg] * atv;
            }
        }
#pragma unroll
        for (int reg = 0; reg < 4; reg++) {
            ushort4 pk;
            pk.x = f2bf(acc4[0][reg]); pk.y = f2bf(acc4[1][reg]);
            pk.z = f2bf(acc4[2][reg]); pk.w = f2bf(acc4[3][reg]);
            int row = m0 + quad * 4 + reg;
            *(ushort4*)(hp2 + (size_t)row * 256 + fc * 4) = pk;
        }
    }
#pragma unroll
    for (int off = 1; off < 16; off <<= 1)
#pragma unroll
        for (int r = 0; r < 4; r++)
#pragma unroll
            for (int q2 = 0; q2 < 4; q2++) {
                sp[r][q2] += __shfl_xor(sp[r][q2], off, 64);
                tp[r][q2] += __shfl_xor(tp[r][q2], off, 64);
            }
    float sv = 0.f, tv = 0.f;
#pragma unroll
    for (int r = 0; r < 4; r++)
#pragma unroll
        for (int q2 = 0; q2 < 4; q2++) {
            bool sel = (mi == r * 4 + q2);
            sv = sel ? sp[r][q2] : sv;
            tv = sel ? tp[r][q2] : tv;
        }
    int rr = m0 + quad * 4 + (mi >> 2);
    sb[rr * 4 + (mi & 3)] = sv;
    tb[rr * 4 + (mi & 3)] = tv;
}

// ---------------------------------------------------------------------------
// passB4: one wave per user node (lane = feature).  n/beg/end/srcl/sb loads
// are wave-uniform -> scalar; 4-edge unroll for gather MLP.  Single pass,
// writes bf16 ret slice directly (no f32 ta).
// ---------------------------------------------------------------------------
__global__ __launch_bounds__(256) void passB4(const unsigned int* __restrict__ rowptr,
                                              const int* __restrict__ srcl,
                                              const float* __restrict__ sb,
                                              const float* __restrict__ tb,
                                              const unsigned short* __restrict__ hp2,
                                              unsigned short* __restrict__ ret, int kslice)
{
    int n = __builtin_amdgcn_readfirstlane(blockIdx.x * 4 + (threadIdx.x >> 6));
    int f = threadIdx.x & 63;
    unsigned int beg = rowptr[n], end = rowptr[n + 1];
    float4 t4 = *(const float4*)(tb + (size_t)n * 4);
    float num0 = 0.f, num1 = 0.f, num2 = 0.f, num3 = 0.f;
    float den0 = 0.f, den1 = 0.f, den2 = 0.f, den3 = 0.f;
    for (unsigned int p = beg; p < end; p += 4) {
        unsigned int rem = end - p;
        int s0 = srcl[p];
        int s1 = (rem > 1) ? srcl[p + 1] : s0;
        int s2 = (rem > 2) ? srcl[p + 2] : s0;
        int s3 = (rem > 3) ? srcl[p + 3] : s0;
        int ss[4] = {s0, s1, s2, s3};
        float valid[4];
        valid[0] = 1.f;
        valid[1] = (rem > 1) ? 1.f : 0.f;
        valid[2] = (rem > 2) ? 1.f : 0.f;
        valid[3] = (rem > 3) ? 1.f : 0.f;
        ushort4 hv[4];
#pragma unroll
        for (int j = 0; j < 4; j++) hv[j] = *(const ushort4*)(hp2 + (size_t)ss[j] * 256 + f * 4);
#pragma unroll
        for (int j = 0; j < 4; j++) {
            float4 sv = *(const float4*)(sb + (size_t)ss[j] * 4);
            float v0 = sv.x + t4.x, v1 = sv.y + t4.y, v2 = sv.z + t4.z, v3 = sv.w + t4.w;
            v0 = (v0 >= 0.f) ? v0 : 0.2f * v0;  v1 = (v1 >= 0.f) ? v1 : 0.2f * v1;
            v2 = (v2 >= 0.f) ? v2 : 0.2f * v2;  v3 = (v3 >= 0.f) ? v3 : 0.2f * v3;
            float e0 = valid[j] * __expf(v0), e1 = valid[j] * __expf(v1);
            float e2 = valid[j] * __expf(v2), e3 = valid[j] * __expf(v3);
            den0 += e0; den1 += e1; den2 += e2; den3 += e3;
            num0 += e0 * bf2f(hv[j].x); num1 += e1 * bf2f(hv[j].y);
            num2 += e2 * bf2f(hv[j].z); num3 += e3 * bf2f(hv[j].w);
        }
    }
    float r = 0.25f * (num0 / (den0 + 1e-16f) + num1 / (den1 + 1e-16f)
                     + num2 / (den2 + 1e-16f) + num3 / (den3 + 1e-16f));
    ret[(size_t)n * 256 + kslice * 64 + f] = f2bf(r);
}

// ---------------------------------------------------------------------------
// qscore2: per 16-row tile, fw1 = h@w1 in-register; per k: scores = tanh(..).m
// ---------------------------------------------------------------------------
__global__ __launch_bounds__(256) void qscore2(const unsigned short* __restrict__ h,
                                               const unsigned short* __restrict__ w1T,
                                               const unsigned short* __restrict__ retA,
                                               const unsigned short* __restrict__ w2T,
                                               const unsigned short* __restrict__ mvec,
                                               float* __restrict__ scores, int M)
{
    int wave = (blockIdx.x * 256 + threadIdx.x) >> 6;
    int lane = threadIdx.x & 63;
    int m0 = wave * 16;
    if (m0 >= M) return;
    int mi = lane & 15, quad = lane >> 4;

    floatx4 fw[4];
#pragma unroll
    for (int nt = 0; nt < 4; nt++) fw[nt] = (floatx4){0.f, 0.f, 0.f, 0.f};
#pragma unroll
    for (int kk = 0; kk < 4; kk++) {
        short8 a = *(const short8*)(h + (size_t)(m0 + mi) * FIN + kk * 32 + quad * 8);
#pragma unroll
        for (int nt = 0; nt < 4; nt++) {
            short8 b = *(const short8*)(w1T + (size_t)((kk * 4 + quad) * 64 + nt * 16 + mi) * 8);
            fw[nt] = __builtin_amdgcn_mfma_f32_16x16x32_bf16(a, b, fw[nt], 0, 0, 0);
        }
    }

    for (int k = 0; k < KKIND; k++) {
        floatx4 acc[4];
#pragma unroll
        for (int nt = 0; nt < 4; nt++) acc[nt] = (floatx4){0.f, 0.f, 0.f, 0.f};
#pragma unroll
        for (int kk = 0; kk < 2; kk++) {
            short8 a = *(const short8*)(retA + (size_t)(m0 + mi) * 256 + k * 64 + kk * 32 + quad * 8);
#pragma unroll
            for (int nt = 0; nt < 4; nt++) {
                short8 b = *(const short8*)(w2T + (size_t)((kk * 4 + quad) * 64 + nt * 16 + mi) * 8);
                acc[nt] = __builtin_amdgcn_mfma_f32_16x16x32_bf16(a, b, acc[nt], 0, 0, 0);
            }
        }
        float part[4] = {0.f, 0.f, 0.f, 0.f};
#pragma unroll
        for (int nt = 0; nt < 4; nt++) {
            int col = nt * 16 + mi;
            float mval = bf2f(mvec[col]);
#pragma unroll
            for (int reg = 0; reg < 4; reg++) {
                float x = acc[nt][reg] + fw[nt][reg];
                float q = 1.f - 2.f / (1.f + __expf(2.f * x));   // tanh, NaN-free
                part[reg] += q * mval;
            }
        }
#pragma unroll
        for (int off = 1; off < 16; off <<= 1)
#pragma unroll
            for (int reg = 0; reg < 4; reg++) part[reg] += __shfl_xor(part[reg], off, 64);
        if (mi == 0) {
#pragma unroll
            for (int reg = 0; reg < 4; reg++)
                scores[(size_t)(m0 + quad * 4 + reg) * 3 + k] = part[reg];
        }
    }
}

// ---------------------------------------------------------------------------
// beta = softmax(scores); ret[:,192:256] = bf16(sum_k beta_k * ret_k)
// ---------------------------------------------------------------------------
__global__ __launch_bounds__(256) void fuse_kernel(const float* __restrict__ scores,
                                                   unsigned short* __restrict__ ret)
{
    int n = blockIdx.x * 4 + (threadIdx.x >> 6);
    int f = threadIdx.x & 63;
    float s0 = scores[n * 3 + 0], s1 = scores[n * 3 + 1], s2 = scores[n * 3 + 2];
    float mx = fmaxf(s0, fmaxf(s1, s2));
    float e0 = __expf(s0 - mx), e1 = __expf(s1 - mx), e2 = __expf(s2 - mx);
    float inv = 1.f / (e0 + e1 + e2);
    const unsigned short* row = ret + (size_t)n * 256;
    float fu = (e0 * bf2f(row[f]) + e1 * bf2f(row[64 + f]) + e2 * bf2f(row[128 + f])) * inv;
    ret[(size_t)n * 256 + 192 + f] = f2bf(fu);
}

// ---------------------------------------------------------------------------
// logits = ret(M x 256) @ fcwT + bias, fused log_softmax -> out (dtype per flag)
// ---------------------------------------------------------------------------
__global__ __launch_bounds__(256) void fc_lsm(const unsigned short* __restrict__ A,
                                              const unsigned short* __restrict__ fcwT,
                                              const unsigned short* __restrict__ bias,
                                              const int* __restrict__ flagp,
                                              void* __restrict__ out, int M)
{
    int wave = (blockIdx.x * 256 + threadIdx.x) >> 6;
    int lane = threadIdx.x & 63;
    int m0 = wave * 16;
    if (m0 >= M) return;
    int mi = lane & 15, quad = lane >> 4;
    floatx4 acc[3];
#pragma unroll
    for (int nt = 0; nt < 3; nt++) acc[nt] = (floatx4){0.f, 0.f, 0.f, 0.f};
#pragma unroll
    for (int kk = 0; kk < 8; kk++) {
        short8 a = *(const short8*)(A + (size_t)(m0 + mi) * 256 + kk * 32 + quad * 8);
#pragma unroll
        for (int nt = 0; nt < 3; nt++) {
            short8 b = *(const short8*)(fcwT + (size_t)((kk * 4 + quad) * 48 + nt * 16 + mi) * 8);
            acc[nt] = __builtin_amdgcn_mfma_f32_16x16x32_bf16(a, b, acc[nt], 0, 0, 0);
        }
    }
    int fl = *flagp;
    float bv[3]; bool ok[3];
#pragma unroll
    for (int nt = 0; nt < 3; nt++) {
        int col = nt * 16 + mi;
        ok[nt] = (col < NCLS);
        bv[nt] = ok[nt] ? bf2f(bias[col]) : 0.f;
    }
#pragma unroll
    for (int reg = 0; reg < 4; reg++) {
        float v[3];
#pragma unroll
        for (int nt = 0; nt < 3; nt++)
            v[nt] = ok[nt] ? (acc[nt][reg] + bv[nt]) : -3.4e38f;
        float mx = fmaxf(fmaxf(v[0], v[1]), v[2]);
#pragma unroll
        for (int off = 1; off < 16; off <<= 1) mx = fmaxf(mx, __shfl_xor(mx, off, 64));
        float s = 0.f;
#pragma unroll
        for (int nt = 0; nt < 3; nt++) s += ok[nt] ? __expf(v[nt] - mx) : 0.f;
#pragma unroll
        for (int off = 1; off < 16; off <<= 1) s += __shfl_xor(s, off, 64);
        float lse = mx + __logf(s);
        int row = m0 + quad * 4 + reg;
#pragma unroll
        for (int nt = 0; nt < 3; nt++) {
            int col = nt * 16 + mi;
            if (col < NCLS) {
                float ls = v[nt] - lse;
                size_t idx = (size_t)row * NCLS + col;
                if (fl) ((float*)out)[idx] = ls;
                else    ((unsigned short*)out)[idx] = f2bf(ls);
            }
        }
    }
}

extern "C" void kernel_launch(void* const* d_in, const int* in_sizes, int n_in,
                              void* d_out, int out_size, void* d_ws, size_t ws_size,
                              hipStream_t stream)
{
    (void)in_sizes; (void)n_in; (void)out_size; (void)ws_size;
    const int* ei = (const int*)d_in[1];

    char* ws = (char*)d_ws;
    unsigned short* conv = (unsigned short*)ws;                 // 13,044,944 B
    unsigned short* hc   = conv + OFF_H;
    unsigned short* wc   = conv + OFF_W;
    unsigned short* asrc = conv + OFF_ASRC;
    unsigned short* atrg = conv + OFF_ATRG;
    unsigned short* w1c  = conv + OFF_W1;
    unsigned short* w2c  = conv + OFF_W2;
    unsigned short* mc   = conv + OFF_M;
    unsigned short* fcwc = conv + OFF_FCW;
    unsigned short* fcbc = conv + OFF_FCB;
    int* flag             = (int*)(ws + 13044944);
    unsigned short* wT    = (unsigned short*)(ws + 13045248);   //    196,608 B
    unsigned short* w1T   = (unsigned short*)(ws + 13241856);   //     16,384 B
    unsigned short* w2T   = (unsigned short*)(ws + 13258240);   //      8,192 B
    unsigned short* fcwT  = (unsigned short*)(ws + 13266432);   //     24,576 B
    unsigned int* partials= (unsigned int*)(ws + 13291008);     //        256 B
    unsigned int* cnt     = (unsigned int*)(ws + 13291264);     //    480,000 B
    unsigned int* rowptr  = (unsigned int*)(ws + 13771264);     //    480,016 B
    int* srcl             = (int*)(ws + 14251280);              //  4,800,000 B
    float* sbuf           = (float*)(ws + 19051280);            //    800,000 B
    float* tbuf           = (float*)(ws + 19851280);            //    800,000 B
    unsigned short* hp2   = (unsigned short*)(ws + 20651280);   // 25,600,000 B
    unsigned short* ret   = (unsigned short*)(ws + 46251280);   // 20,480,000 B
    float* scores         = (float*)(ws + 66731280);            //    480,000 B -> 67,211,280

    detect_kernel<<<1, 256, 0, stream>>>((const unsigned short*)d_in[0], flag);
    conv_kernel<<<(CONV_TOT / 8 + 255) / 256, 256, 0, stream>>>(
        d_in[0], d_in[2], d_in[3], d_in[4], d_in[5], d_in[6], d_in[7], d_in[8], d_in[9],
        flag, conv);

    repack_w<<<48, 256, 0, stream>>>(wc, wT);
    repack_small<<<12, 256, 0, stream>>>(w1c, w2c, fcwc, w1T, w2T, fcwT);

    hipMemsetAsync(cnt, 0, (size_t)KKIND * NUSER * 4, stream);
    hist3<<<dim3(1563, 3), 256, 0, stream>>>(ei, cnt);
    scanA<<<dim3(SCB, 3), 256, 0, stream>>>(cnt, partials);
    scanB<<<1, 256, 0, stream>>>(partials, rowptr);
    scanC<<<dim3(SCB, 3), 256, 0, stream>>>(cnt, partials, rowptr);
    hipMemsetAsync(cnt, 0, (size_t)KKIND * NUSER * 4, stream);
    scatter3<<<dim3(1563, 3), 256, 0, stream>>>(ei, rowptr, cnt, srcl);

    for (int k = 0; k < KKIND; k++) {
        hp_gemm<<<782, 256, 0, stream>>>(hc, wT + (size_t)k * 32768,
                                         asrc + k * HHEAD * FOUT, atrg + k * HHEAD * FOUT,
                                         hp2, sbuf, tbuf);
        passB4<<<NUSER / 4, 256, 0, stream>>>(rowptr + (size_t)k * (NUSER + 1),
                                              srcl + (size_t)k * EE,
                                              sbuf, tbuf, hp2, ret, k);
    }

    qscore2<<<625, 256, 0, stream>>>(hc, w1T, ret, w2T, mc, scores, NUSER);
    fuse_kernel<<<NUSER / 4, 256, 0, stream>>>(scores, ret);
    fc_lsm<<<625, 256, 0, stream>>>(ret, fcwT, fcbc, flag, d_out, NUSER);
}

// Round 6
// 407.251 us; speedup vs baseline: 1.6052x; 1.0417x over previous
//
#include <hip/hip_runtime.h>
#include <hip/hip_bf16.h>

#define NN    50000
#define NUSER 40000
#define EE    400000
#define KKIND 3
#define HHEAD 4
#define FIN   128
#define FOUT  64
#define NCLS  40

typedef __attribute__((ext_vector_type(8))) short short8;
typedef __attribute__((ext_vector_type(4))) float floatx4;

__device__ __forceinline__ float bf2f(unsigned short u) {
    unsigned int v = ((unsigned int)u) << 16;
    return __uint_as_float(v);
}
__device__ __forceinline__ unsigned short f2bf(float f) {
    unsigned int u = __float_as_uint(f);
    unsigned int r = (u + 0x7FFFu + ((u >> 16) & 1u)) >> 16;  // RNE
    return (unsigned short)r;
}

// conv-region element offsets (u16 elements) — all multiples of 8
#define OFF_H    0
#define OFF_W    6400000
#define OFF_ASRC 6498304
#define OFF_ATRG 6499072
#define OFF_W1   6499840
#define OFF_W2   6508032
#define OFF_M    6512128
#define OFF_FCW  6512192
#define OFF_FCB  6522432
#define CONV_TOT 6522472

// ---------------------------------------------------------------------------
// dtype detect (f32 vs bf16 float inputs)
// ---------------------------------------------------------------------------
__global__ __launch_bounds__(256) void detect_kernel(const unsigned short* __restrict__ hraw,
                                                     int* __restrict__ flag)
{
    __shared__ int cnt;
    if (threadIdx.x == 0) cnt = 0;
    __syncthreads();
    int local = 0;
#pragma unroll
    for (int j = 0; j < 8; j++) {
        unsigned short u = hraw[threadIdx.x * 8 + j];
        int ex = (u >> 7) & 0xFF;
        if (ex >= 0x90) local++;
    }
    atomicAdd(&cnt, local);
    __syncthreads();
    if (threadIdx.x == 0) *flag = (cnt > 100) ? 1 : 0;
}

// 8 u16 elements per thread; segment boundaries all %8==0
__global__ __launch_bounds__(256) void conv_kernel(const void* __restrict__ p0, const void* __restrict__ p2,
                                                   const void* __restrict__ p3, const void* __restrict__ p4,
                                                   const void* __restrict__ p5, const void* __restrict__ p6,
                                                   const void* __restrict__ p7, const void* __restrict__ p8,
                                                   const void* __restrict__ p9,
                                                   const int* __restrict__ flagp,
                                                   unsigned short* __restrict__ dst)
{
    int tid = (blockIdx.x * 256 + threadIdx.x) * 8;
    if (tid >= CONV_TOT) return;
    const void* src; int li;
    if      (tid < OFF_W)    { src = p0; li = tid - OFF_H; }
    else if (tid < OFF_ASRC) { src = p2; li = tid - OFF_W; }
    else if (tid < OFF_ATRG) { src = p3; li = tid - OFF_ASRC; }
    else if (tid < OFF_W1)   { src = p4; li = tid - OFF_ATRG; }
    else if (tid < OFF_W2)   { src = p5; li = tid - OFF_W1; }
    else if (tid < OFF_M)    { src = p6; li = tid - OFF_W2; }
    else if (tid < OFF_FCW)  { src = p7; li = tid - OFF_M; }
    else if (tid < OFF_FCB)  { src = p8; li = tid - OFF_FCW; }
    else                     { src = p9; li = tid - OFF_FCB; }
    if (*flagp) {
        const float* fp = (const float*)src + li;
        float4 x = *(const float4*)fp;
        float4 y = *(const float4*)(fp + 4);
        uint4 o;
        o.x = (unsigned int)f2bf(x.x) | ((unsigned int)f2bf(x.y) << 16);
        o.y = (unsigned int)f2bf(x.z) | ((unsigned int)f2bf(x.w) << 16);
        o.z = (unsigned int)f2bf(y.x) | ((unsigned int)f2bf(y.y) << 16);
        o.w = (unsigned int)f2bf(y.z) | ((unsigned int)f2bf(y.w) << 16);
        *(uint4*)(dst + tid) = o;
    } else {
        *(uint4*)(dst + tid) = *(const uint4*)((const unsigned short*)src + li);
    }
}

// ---------------------------------------------------------------------------
// B-matrix repacks into MFMA fragment layout
// ---------------------------------------------------------------------------
__global__ __launch_bounds__(256) void repack_w(const unsigned short* __restrict__ w,
                                                unsigned short* __restrict__ wT)
{
    int tid = blockIdx.x * 256 + threadIdx.x;       // 3*4*16*64 = 12288
    if (tid >= 12288) return;
    int f = tid & 63, g = (tid >> 6) & 15, h = (tid >> 10) & 3, k = tid >> 12;
    const unsigned short* src = w + (size_t)(k * 4 + h) * 8192 + f;
    unsigned short* dst = wT + (size_t)tid * 8;
#pragma unroll
    for (int j = 0; j < 8; j++) dst[j] = src[(size_t)(g * 8 + j) * 64];
}

__global__ __launch_bounds__(256) void repack_small(const unsigned short* __restrict__ w1,
                                                    const unsigned short* __restrict__ w2,
                                                    const unsigned short* __restrict__ fcw,
                                                    unsigned short* __restrict__ w1T,
                                                    unsigned short* __restrict__ w2T,
                                                    unsigned short* __restrict__ fcwT)
{
    int tid = blockIdx.x * 256 + threadIdx.x;
    if (tid < 1024) {                                 // w1: g in [0,16), c in [0,64)
        int c = tid & 63, g = tid >> 6;
#pragma unroll
        for (int j = 0; j < 8; j++) w1T[(size_t)(g * 64 + c) * 8 + j] = w1[(size_t)(g * 8 + j) * 64 + c];
    } else if (tid < 1536) {                          // w2: g in [0,8)
        int t = tid - 1024; int c = t & 63, g = t >> 6;
#pragma unroll
        for (int j = 0; j < 8; j++) w2T[(size_t)(g * 64 + c) * 8 + j] = w2[(size_t)(g * 8 + j) * 64 + c];
    } else if (tid < 3072) {                          // fcw: g in [0,32), c in [0,48)
        int t = tid - 1536; int c = t % 48, g = t / 48;
#pragma unroll
        for (int j = 0; j < 8; j++)
            fcwT[(size_t)(g * 48 + c) * 8 + j] = (c < NCLS) ? fcw[(size_t)(g * 8 + j) * NCLS + c] : (unsigned short)0;
    }
}

// ---------------------------------------------------------------------------
// CSR sort by target (targets < NUSER only).  hist also RECORDS each edge's
// rank within its target segment (the atomicAdd return), so the scatter pass
// needs no atomics at all.
// ---------------------------------------------------------------------------
__global__ __launch_bounds__(256) void hist3(const int* __restrict__ ei,
                                             unsigned int* __restrict__ cnt,
                                             unsigned int* __restrict__ rank)
{
    int e = blockIdx.x * 256 + threadIdx.x;
    int k = blockIdx.y;
    if (e >= EE) return;
    int tn = ei[(size_t)k * 2 * EE + EE + e];
    if (tn < NUSER)
        rank[(size_t)k * EE + e] = atomicAdd(&cnt[(size_t)k * NUSER + tn], 1u);
}

// 3-phase multi-block exclusive scan
#define SCB 20          // blocks per kind, 2048 elements each
__global__ __launch_bounds__(256) void scanA(const unsigned int* __restrict__ cnt,
                                             unsigned int* __restrict__ partials)
{
    int k = blockIdx.y, b = blockIdx.x;
    const unsigned int* c = cnt + (size_t)k * NUSER;
    int base = b * 2048 + threadIdx.x * 8;
    unsigned int s = 0;
#pragma unroll
    for (int j = 0; j < 8; j++) { int idx = base + j; if (idx < NUSER) s += c[idx]; }
#pragma unroll
    for (int off = 1; off < 64; off <<= 1) s += __shfl_xor(s, off, 64);
    __shared__ unsigned int wsum[4];
    int lane = threadIdx.x & 63, wid = threadIdx.x >> 6;
    if (lane == 0) wsum[wid] = s;
    __syncthreads();
    if (threadIdx.x == 0) partials[k * SCB + b] = wsum[0] + wsum[1] + wsum[2] + wsum[3];
}

__global__ __launch_bounds__(256) void scanB(unsigned int* __restrict__ partials,
                                             unsigned int* __restrict__ rowptr)
{
    int wid = threadIdx.x >> 6, lane = threadIdx.x & 63;
    if (wid >= KKIND) return;
    unsigned int v = (lane < SCB) ? partials[wid * SCB + lane] : 0u;
    unsigned int inc = v;
#pragma unroll
    for (int off = 1; off < 32; off <<= 1) {
        unsigned int u = __shfl_up(inc, off, 64);
        if (lane >= off) inc += u;
    }
    if (lane < SCB) partials[wid * SCB + lane] = inc - v;      // exclusive
    if (lane == SCB - 1) rowptr[(size_t)wid * (NUSER + 1) + NUSER] = inc;  // total
}

__global__ __launch_bounds__(256) void scanC(const unsigned int* __restrict__ cnt,
                                             const unsigned int* __restrict__ partials,
                                             unsigned int* __restrict__ rowptr)
{
    int k = blockIdx.y, b = blockIdx.x;
    const unsigned int* c = cnt + (size_t)k * NUSER;
    unsigned int* rp = rowptr + (size_t)k * (NUSER + 1);
    int lane = threadIdx.x & 63, wid = threadIdx.x >> 6;
    int base = b * 2048 + threadIdx.x * 8;
    unsigned int vals[8]; unsigned int s = 0;
#pragma unroll
    for (int j = 0; j < 8; j++) { int idx = base + j; vals[j] = (idx < NUSER) ? c[idx] : 0u; s += vals[j]; }
    unsigned int inc = s;
#pragma unroll
    for (int off = 1; off < 64; off <<= 1) {
        unsigned int u = __shfl_up(inc, off, 64);
        if (lane >= off) inc += u;
    }
    __shared__ unsigned int wsum[4];
    if (lane == 63) wsum[wid] = inc;
    __syncthreads();
    unsigned int woff = 0;
    for (int i = 0; i < wid; i++) woff += wsum[i];
    unsigned int run = partials[k * SCB + b] + woff + (inc - s);
#pragma unroll
    for (int j = 0; j < 8; j++) {
        int idx = base + j;
        if (idx < NUSER) { rp[idx] = run; run += vals[j]; }
    }
}

// atomic-free scatter: p = rowptr[tn] + rank[e]
__global__ __launch_bounds__(256) void scatter3(const int* __restrict__ ei,
                                                const unsigned int* __restrict__ rowptr,
                                                const unsigned int* __restrict__ rank,
                                                int* __restrict__ srcl)
{
    int e = blockIdx.x * 256 + threadIdx.x;
    int k = blockIdx.y;
    if (e >= EE) return;
    const int* srcA = ei + (size_t)k * 2 * EE;
    int tn = srcA[EE + e];
    if (tn >= NUSER) return;
    unsigned int p = rowptr[(size_t)k * (NUSER + 1) + tn] + rank[(size_t)k * EE + e];
    srcl[(size_t)k * EE + p] = srcA[e];
}

// ---------------------------------------------------------------------------
// hp2 = h @ w[k] in layout [n][f][4heads] bf16, fused s/t epilogue.
// ---------------------------------------------------------------------------
__global__ __launch_bounds__(256) void hp_gemm(const unsigned short* __restrict__ h,
                                               const unsigned short* __restrict__ wTk,
                                               const unsigned short* __restrict__ ak_src,
                                               const unsigned short* __restrict__ ak_trg,
                                               unsigned short* __restrict__ hp2,
                                               float* __restrict__ sb, float* __restrict__ tb)
{
    int wave = (blockIdx.x * 256 + threadIdx.x) >> 6;
    int lane = threadIdx.x & 63;
    if (wave >= NN / 16) return;
    int m0 = wave * 16;
    int mi = lane & 15, quad = lane >> 4;

    short8 a[4];
    const unsigned short* hrow = h + (size_t)(m0 + mi) * FIN + quad * 8;
#pragma unroll
    for (int kk = 0; kk < 4; kk++) a[kk] = *(const short8*)(hrow + kk * 32);

    float sp[4][4], tp[4][4];
#pragma unroll
    for (int r = 0; r < 4; r++)
#pragma unroll
        for (int q2 = 0; q2 < 4; q2++) { sp[r][q2] = 0.f; tp[r][q2] = 0.f; }

#pragma unroll
    for (int j = 0; j < 4; j++) {
        int fc = j * 16 + mi;
        floatx4 acc4[4];
#pragma unroll
        for (int hh = 0; hh < 4; hh++) {
            floatx4 acc = {0.f, 0.f, 0.f, 0.f};
#pragma unroll
            for (int kk = 0; kk < 4; kk++) {
                short8 b = *(const short8*)(wTk + (size_t)((hh * 16 + kk * 4 + quad) * 64 + fc) * 8);
                acc = __builtin_amdgcn_mfma_f32_16x16x32_bf16(a[kk], b, acc, 0, 0, 0);
            }
            acc4[hh] = acc;
            float asv = bf2f(ak_src[hh * 64 + fc]);
            float atv = bf2f(ak_trg[hh * 64 + fc]);
#pragma unroll
            for (int reg = 0; reg < 4; reg++) {
                sp[reg][hh] += acc[reg] * asv;
                tp[reg][hh] += acc[reg] * atv;
            }
        }
#pragma unroll
        for (int reg = 0; reg < 4; reg++) {
            ushort4 pk;
            pk.x = f2bf(acc4[0][reg]); pk.y = f2bf(acc4[1][reg]);
            pk.z = f2bf(acc4[2][reg]); pk.w = f2bf(acc4[3][reg]);
            int row = m0 + quad * 4 + reg;
            *(ushort4*)(hp2 + (size_t)row * 256 + fc * 4) = pk;
        }
    }
#pragma unroll
    for (int off = 1; off < 16; off <<= 1)
#pragma unroll
        for (int r = 0; r < 4; r++)
#pragma unroll
            for (int q2 = 0; q2 < 4; q2++) {
                sp[r][q2] += __shfl_xor(sp[r][q2], off, 64);
                tp[r][q2] += __shfl_xor(tp[r][q2], off, 64);
            }
    float sv = 0.f, tv = 0.f;
#pragma unroll
    for (int r = 0; r < 4; r++)
#pragma unroll
        for (int q2 = 0; q2 < 4; q2++) {
            bool sel = (mi == r * 4 + q2);
            sv = sel ? sp[r][q2] : sv;
            tv = sel ? tp[r][q2] : tv;
        }
    int rr = m0 + quad * 4 + (mi >> 2);
    sb[rr * 4 + (mi & 3)] = sv;
    tb[rr * 4 + (mi & 3)] = tv;
}

// ---------------------------------------------------------------------------
// passB5: one wave per user node (lane = feature).  Wave-uniform scalar loads
// for srcl/sb; 8-edge unroll (avg degree ~8) for gather MLP.  Single pass,
// writes bf16 ret slice directly.
// ---------------------------------------------------------------------------
__global__ __launch_bounds__(256) void passB5(const unsigned int* __restrict__ rowptr,
                                              const int* __restrict__ srcl,
                                              const float* __restrict__ sb,
                                              const float* __restrict__ tb,
                                              const unsigned short* __restrict__ hp2,
                                              unsigned short* __restrict__ ret, int kslice)
{
    int n = __builtin_amdgcn_readfirstlane(blockIdx.x * 4 + (threadIdx.x >> 6));
    int f = threadIdx.x & 63;
    unsigned int beg = rowptr[n], end = rowptr[n + 1];
    float4 t4 = *(const float4*)(tb + (size_t)n * 4);
    float num0 = 0.f, num1 = 0.f, num2 = 0.f, num3 = 0.f;
    float den0 = 0.f, den1 = 0.f, den2 = 0.f, den3 = 0.f;
    for (unsigned int p = beg; p < end; p += 8) {
        int ss[8]; float valid[8];
#pragma unroll
        for (int j = 0; j < 8; j++) {
            unsigned int q = (p + j < end) ? (p + j) : p;
            ss[j] = srcl[q];
            valid[j] = (p + j < end) ? 1.f : 0.f;
        }
        ushort4 hv[8];
#pragma unroll
        for (int j = 0; j < 8; j++) hv[j] = *(const ushort4*)(hp2 + (size_t)ss[j] * 256 + f * 4);
#pragma unroll
        for (int j = 0; j < 8; j++) {
            float4 sv = *(const float4*)(sb + (size_t)ss[j] * 4);
            float v0 = sv.x + t4.x, v1 = sv.y + t4.y, v2 = sv.z + t4.z, v3 = sv.w + t4.w;
            v0 = (v0 >= 0.f) ? v0 : 0.2f * v0;  v1 = (v1 >= 0.f) ? v1 : 0.2f * v1;
            v2 = (v2 >= 0.f) ? v2 : 0.2f * v2;  v3 = (v3 >= 0.f) ? v3 : 0.2f * v3;
            float e0 = valid[j] * __expf(v0), e1 = valid[j] * __expf(v1);
            float e2 = valid[j] * __expf(v2), e3 = valid[j] * __expf(v3);
            den0 += e0; den1 += e1; den2 += e2; den3 += e3;
            num0 += e0 * bf2f(hv[j].x); num1 += e1 * bf2f(hv[j].y);
            num2 += e2 * bf2f(hv[j].z); num3 += e3 * bf2f(hv[j].w);
        }
    }
    float r = 0.25f * (num0 / (den0 + 1e-16f) + num1 / (den1 + 1e-16f)
                     + num2 / (den2 + 1e-16f) + num3 / (den3 + 1e-16f));
    ret[(size_t)n * 256 + kslice * 64 + f] = f2bf(r);
}

// ---------------------------------------------------------------------------
// qscore2: per 16-row tile, fw1 = h@w1 in-register; per k: scores = tanh(..).m
// ---------------------------------------------------------------------------
__global__ __launch_bounds__(256) void qscore2(const unsigned short* __restrict__ h,
                                               const unsigned short* __restrict__ w1T,
                                               const unsigned short* __restrict__ retA,
                                               const unsigned short* __restrict__ w2T,
                                               const unsigned short* __restrict__ mvec,
                                               float* __restrict__ scores, int M)
{
    int wave = (blockIdx.x * 256 + threadIdx.x) >> 6;
    int lane = threadIdx.x & 63;
    int m0 = wave * 16;
    if (m0 >= M) return;
    int mi = lane & 15, quad = lane >> 4;

    floatx4 fw[4];
#pragma unroll
    for (int nt = 0; nt < 4; nt++) fw[nt] = (floatx4){0.f, 0.f, 0.f, 0.f};
#pragma unroll
    for (int kk = 0; kk < 4; kk++) {
        short8 a = *(const short8*)(h + (size_t)(m0 + mi) * FIN + kk * 32 + quad * 8);
#pragma unroll
        for (int nt = 0; nt < 4; nt++) {
            short8 b = *(const short8*)(w1T + (size_t)((kk * 4 + quad) * 64 + nt * 16 + mi) * 8);
            fw[nt] = __builtin_amdgcn_mfma_f32_16x16x32_bf16(a, b, fw[nt], 0, 0, 0);
        }
    }

    for (int k = 0; k < KKIND; k++) {
        floatx4 acc[4];
#pragma unroll
        for (int nt = 0; nt < 4; nt++) acc[nt] = (floatx4){0.f, 0.f, 0.f, 0.f};
#pragma unroll
        for (int kk = 0; kk < 2; kk++) {
            short8 a = *(const short8*)(retA + (size_t)(m0 + mi) * 256 + k * 64 + kk * 32 + quad * 8);
#pragma unroll
            for (int nt = 0; nt < 4; nt++) {
                short8 b = *(const short8*)(w2T + (size_t)((kk * 4 + quad) * 64 + nt * 16 + mi) * 8);
                acc[nt] = __builtin_amdgcn_mfma_f32_16x16x32_bf16(a, b, acc[nt], 0, 0, 0);
            }
        }
        float part[4] = {0.f, 0.f, 0.f, 0.f};
#pragma unroll
        for (int nt = 0; nt < 4; nt++) {
            int col = nt * 16 + mi;
            float mval = bf2f(mvec[col]);
#pragma unroll
            for (int reg = 0; reg < 4; reg++) {
                float x = acc[nt][reg] + fw[nt][reg];
                float q = 1.f - 2.f / (1.f + __expf(2.f * x));   // tanh, NaN-free
                part[reg] += q * mval;
            }
        }
#pragma unroll
        for (int off = 1; off < 16; off <<= 1)
#pragma unroll
            for (int reg = 0; reg < 4; reg++) part[reg] += __shfl_xor(part[reg], off, 64);
        if (mi == 0) {
#pragma unroll
            for (int reg = 0; reg < 4; reg++)
                scores[(size_t)(m0 + quad * 4 + reg) * 3 + k] = part[reg];
        }
    }
}

// ---------------------------------------------------------------------------
// beta = softmax(scores); ret[:,192:256] = bf16(sum_k beta_k * ret_k)
// ---------------------------------------------------------------------------
__global__ __launch_bounds__(256) void fuse_kernel(const float* __restrict__ scores,
                                                   unsigned short* __restrict__ ret)
{
    int n = blockIdx.x * 4 + (threadIdx.x >> 6);
    int f = threadIdx.x & 63;
    float s0 = scores[n * 3 + 0], s1 = scores[n * 3 + 1], s2 = scores[n * 3 + 2];
    float mx = fmaxf(s0, fmaxf(s1, s2));
    float e0 = __expf(s0 - mx), e1 = __expf(s1 - mx), e2 = __expf(s2 - mx);
    float inv = 1.f / (e0 + e1 + e2);
    const unsigned short* row = ret + (size_t)n * 256;
    float fu = (e0 * bf2f(row[f]) + e1 * bf2f(row[64 + f]) + e2 * bf2f(row[128 + f])) * inv;
    ret[(size_t)n * 256 + 192 + f] = f2bf(fu);
}

// ---------------------------------------------------------------------------
// logits = ret(M x 256) @ fcwT + bias, fused log_softmax -> out (dtype per flag)
// ---------------------------------------------------------------------------
__global__ __launch_bounds__(256) void fc_lsm(const unsigned short* __restrict__ A,
                                              const unsigned short* __restrict__ fcwT,
                                              const unsigned short* __restrict__ bias,
                                              const int* __restrict__ flagp,
                                              void* __restrict__ out, int M)
{
    int wave = (blockIdx.x * 256 + threadIdx.x) >> 6;
    int lane = threadIdx.x & 63;
    int m0 = wave * 16;
    if (m0 >= M) return;
    int mi = lane & 15, quad = lane >> 4;
    floatx4 acc[3];
#pragma unroll
    for (int nt = 0; nt < 3; nt++) acc[nt] = (floatx4){0.f, 0.f, 0.f, 0.f};
#pragma unroll
    for (int kk = 0; kk < 8; kk++) {
        short8 a = *(const short8*)(A + (size_t)(m0 + mi) * 256 + kk * 32 + quad * 8);
#pragma unroll
        for (int nt = 0; nt < 3; nt++) {
            short8 b = *(const short8*)(fcwT + (size_t)((kk * 4 + quad) * 48 + nt * 16 + mi) * 8);
            acc[nt] = __builtin_amdgcn_mfma_f32_16x16x32_bf16(a, b, acc[nt], 0, 0, 0);
        }
    }
    int fl = *flagp;
    float bv[3]; bool ok[3];
#pragma unroll
    for (int nt = 0; nt < 3; nt++) {
        int col = nt * 16 + mi;
        ok[nt] = (col < NCLS);
        bv[nt] = ok[nt] ? bf2f(bias[col]) : 0.f;
    }
#pragma unroll
    for (int reg = 0; reg < 4; reg++) {
        float v[3];
#pragma unroll
        for (int nt = 0; nt < 3; nt++)
            v[nt] = ok[nt] ? (acc[nt][reg] + bv[nt]) : -3.4e38f;
        float mx = fmaxf(fmaxf(v[0], v[1]), v[2]);
#pragma unroll
        for (int off = 1; off < 16; off <<= 1) mx = fmaxf(mx, __shfl_xor(mx, off, 64));
        float s = 0.f;
#pragma unroll
        for (int nt = 0; nt < 3; nt++) s += ok[nt] ? __expf(v[nt] - mx) : 0.f;
#pragma unroll
        for (int off = 1; off < 16; off <<= 1) s += __shfl_xor(s, off, 64);
        float lse = mx + __logf(s);
        int row = m0 + quad * 4 + reg;
#pragma unroll
        for (int nt = 0; nt < 3; nt++) {
            int col = nt * 16 + mi;
            if (col < NCLS) {
                float ls = v[nt] - lse;
                size_t idx = (size_t)row * NCLS + col;
                if (fl) ((float*)out)[idx] = ls;
                else    ((unsigned short*)out)[idx] = f2bf(ls);
            }
        }
    }
}

extern "C" void kernel_launch(void* const* d_in, const int* in_sizes, int n_in,
                              void* d_out, int out_size, void* d_ws, size_t ws_size,
                              hipStream_t stream)
{
    (void)in_sizes; (void)n_in; (void)out_size; (void)ws_size;
    const int* ei = (const int*)d_in[1];

    char* ws = (char*)d_ws;
    unsigned short* conv = (unsigned short*)ws;                 // 13,044,944 B
    unsigned short* hc   = conv + OFF_H;
    unsigned short* wc   = conv + OFF_W;
    unsigned short* asrc = conv + OFF_ASRC;
    unsigned short* atrg = conv + OFF_ATRG;
    unsigned short* w1c  = conv + OFF_W1;
    unsigned short* w2c  = conv + OFF_W2;
    unsigned short* mc   = conv + OFF_M;
    unsigned short* fcwc = conv + OFF_FCW;
    unsigned short* fcbc = conv + OFF_FCB;
    int* flag             = (int*)(ws + 13044944);
    unsigned short* wT    = (unsigned short*)(ws + 13045248);   //    196,608 B
    unsigned short* w1T   = (unsigned short*)(ws + 13241856);   //     16,384 B
    unsigned short* w2T   = (unsigned short*)(ws + 13258240);   //      8,192 B
    unsigned short* fcwT  = (unsigned short*)(ws + 13266432);   //     24,576 B
    unsigned int* partials= (unsigned int*)(ws + 13291008);     //        256 B
    unsigned int* cnt     = (unsigned int*)(ws + 13291264);     //    480,000 B
    float* scores         = (float*)(ws + 13291264);            // overlay (cnt dead post-scan)
    unsigned int* rowptr  = (unsigned int*)(ws + 13771264);     //    480,256 B
    int* srcl             = (int*)(ws + 14251520);              //  4,800,000 B
    unsigned int* rank    = (unsigned int*)(ws + 19051520);     //  4,800,000 B
    float* sbuf           = (float*)(ws + 23851520);            //    800,000 B
    float* tbuf           = (float*)(ws + 24651520);            //    800,000 B
    unsigned short* hp2   = (unsigned short*)(ws + 25451520);   // 25,600,000 B
    unsigned short* ret   = (unsigned short*)(ws + 51051520);   // 20,480,000 B -> 71,531,520

    detect_kernel<<<1, 256, 0, stream>>>((const unsigned short*)d_in[0], flag);
    conv_kernel<<<(CONV_TOT / 8 + 255) / 256, 256, 0, stream>>>(
        d_in[0], d_in[2], d_in[3], d_in[4], d_in[5], d_in[6], d_in[7], d_in[8], d_in[9],
        flag, conv);

    repack_w<<<48, 256, 0, stream>>>(wc, wT);
    repack_small<<<12, 256, 0, stream>>>(w1c, w2c, fcwc, w1T, w2T, fcwT);

    hipMemsetAsync(cnt, 0, (size_t)KKIND * NUSER * 4, stream);
    hist3<<<dim3(1563, 3), 256, 0, stream>>>(ei, cnt, rank);
    scanA<<<dim3(SCB, 3), 256, 0, stream>>>(cnt, partials);
    scanB<<<1, 256, 0, stream>>>(partials, rowptr);
    scanC<<<dim3(SCB, 3), 256, 0, stream>>>(cnt, partials, rowptr);
    scatter3<<<dim3(1563, 3), 256, 0, stream>>>(ei, rowptr, rank, srcl);

    for (int k = 0; k < KKIND; k++) {
        hp_gemm<<<782, 256, 0, stream>>>(hc, wT + (size_t)k * 32768,
                                         asrc + k * HHEAD * FOUT, atrg + k * HHEAD * FOUT,
                                         hp2, sbuf, tbuf);
        passB5<<<NUSER / 4, 256, 0, stream>>>(rowptr + (size_t)k * (NUSER + 1),
                                              srcl + (size_t)k * EE,
                                              sbuf, tbuf, hp2, ret, k);
    }

    qscore2<<<625, 256, 0, stream>>>(hc, w1T, ret, w2T, mc, scores, NUSER);
    fuse_kernel<<<NUSER / 4, 256, 0, stream>>>(scores, ret);
    fc_lsm<<<625, 256, 0, stream>>>(ret, fcwT, fcbc, flag, d_out, NUSER);
}

// Round 7
// 375.183 us; speedup vs baseline: 1.7424x; 1.0855x over previous
//
#include <hip/hip_runtime.h>
#include <hip/hip_bf16.h>

#define NN    50000
#define NUSER 40000
#define EE    400000
#define KKIND 3
#define HHEAD 4
#define FIN   128
#define FOUT  64
#define NCLS  40

typedef __attribute__((ext_vector_type(8))) short short8;
typedef __attribute__((ext_vector_type(4))) float floatx4;

__device__ __forceinline__ float bf2f(unsigned short u) {
    unsigned int v = ((unsigned int)u) << 16;
    return __uint_as_float(v);
}
__device__ __forceinline__ unsigned short f2bf(float f) {
    unsigned int u = __float_as_uint(f);
    unsigned int r = (u + 0x7FFFu + ((u >> 16) & 1u)) >> 16;  // RNE
    return (unsigned short)r;
}

// conv-region element offsets (u16 elements) — all multiples of 8
#define OFF_H    0
#define OFF_W    6400000
#define OFF_ASRC 6498304
#define OFF_ATRG 6499072
#define OFF_W1   6499840
#define OFF_W2   6508032
#define OFF_M    6512128
#define OFF_FCW  6512192
#define OFF_FCB  6522432
#define CONV_TOT 6522472

// ---------------------------------------------------------------------------
// dtype detect (f32 vs bf16 float inputs)
// ---------------------------------------------------------------------------
__global__ __launch_bounds__(256) void detect_kernel(const unsigned short* __restrict__ hraw,
                                                     int* __restrict__ flag)
{
    __shared__ int cnt;
    if (threadIdx.x == 0) cnt = 0;
    __syncthreads();
    int local = 0;
#pragma unroll
    for (int j = 0; j < 8; j++) {
        unsigned short u = hraw[threadIdx.x * 8 + j];
        int ex = (u >> 7) & 0xFF;
        if (ex >= 0x90) local++;
    }
    atomicAdd(&cnt, local);
    __syncthreads();
    if (threadIdx.x == 0) *flag = (cnt > 100) ? 1 : 0;
}

// 8 u16 elements per thread; segment boundaries all %8==0
__global__ __launch_bounds__(256) void conv_kernel(const void* __restrict__ p0, const void* __restrict__ p2,
                                                   const void* __restrict__ p3, const void* __restrict__ p4,
                                                   const void* __restrict__ p5, const void* __restrict__ p6,
                                                   const void* __restrict__ p7, const void* __restrict__ p8,
                                                   const void* __restrict__ p9,
                                                   const int* __restrict__ flagp,
                                                   unsigned short* __restrict__ dst)
{
    int tid = (blockIdx.x * 256 + threadIdx.x) * 8;
    if (tid >= CONV_TOT) return;
    const void* src; int li;
    if      (tid < OFF_W)    { src = p0; li = tid - OFF_H; }
    else if (tid < OFF_ASRC) { src = p2; li = tid - OFF_W; }
    else if (tid < OFF_ATRG) { src = p3; li = tid - OFF_ASRC; }
    else if (tid < OFF_W1)   { src = p4; li = tid - OFF_ATRG; }
    else if (tid < OFF_W2)   { src = p5; li = tid - OFF_W1; }
    else if (tid < OFF_M)    { src = p6; li = tid - OFF_W2; }
    else if (tid < OFF_FCW)  { src = p7; li = tid - OFF_M; }
    else if (tid < OFF_FCB)  { src = p8; li = tid - OFF_FCW; }
    else                     { src = p9; li = tid - OFF_FCB; }
    if (*flagp) {
        const float* fp = (const float*)src + li;
        float4 x = *(const float4*)fp;
        float4 y = *(const float4*)(fp + 4);
        uint4 o;
        o.x = (unsigned int)f2bf(x.x) | ((unsigned int)f2bf(x.y) << 16);
        o.y = (unsigned int)f2bf(x.z) | ((unsigned int)f2bf(x.w) << 16);
        o.z = (unsigned int)f2bf(y.x) | ((unsigned int)f2bf(y.y) << 16);
        o.w = (unsigned int)f2bf(y.z) | ((unsigned int)f2bf(y.w) << 16);
        *(uint4*)(dst + tid) = o;
    } else {
        *(uint4*)(dst + tid) = *(const uint4*)((const unsigned short*)src + li);
    }
}

// ---------------------------------------------------------------------------
// B-matrix repacks into MFMA fragment layout
// ---------------------------------------------------------------------------
__global__ __launch_bounds__(256) void repack_w(const unsigned short* __restrict__ w,
                                                unsigned short* __restrict__ wT)
{
    int tid = blockIdx.x * 256 + threadIdx.x;       // 3*4*16*64 = 12288
    if (tid >= 12288) return;
    int f = tid & 63, g = (tid >> 6) & 15, h = (tid >> 10) & 3, k = tid >> 12;
    const unsigned short* src = w + (size_t)(k * 4 + h) * 8192 + f;
    unsigned short* dst = wT + (size_t)tid * 8;
#pragma unroll
    for (int j = 0; j < 8; j++) dst[j] = src[(size_t)(g * 8 + j) * 64];
}

__global__ __launch_bounds__(256) void repack_small(const unsigned short* __restrict__ w1,
                                                    const unsigned short* __restrict__ w2,
                                                    const unsigned short* __restrict__ fcw,
                                                    unsigned short* __restrict__ w1T,
                                                    unsigned short* __restrict__ w2T,
                                                    unsigned short* __restrict__ fcwT)
{
    int tid = blockIdx.x * 256 + threadIdx.x;
    if (tid < 1024) {                                 // w1: g in [0,16), c in [0,64)
        int c = tid & 63, g = tid >> 6;
#pragma unroll
        for (int j = 0; j < 8; j++) w1T[(size_t)(g * 64 + c) * 8 + j] = w1[(size_t)(g * 8 + j) * 64 + c];
    } else if (tid < 1536) {                          // w2: g in [0,8)
        int t = tid - 1024; int c = t & 63, g = t >> 6;
#pragma unroll
        for (int j = 0; j < 8; j++) w2T[(size_t)(g * 64 + c) * 8 + j] = w2[(size_t)(g * 8 + j) * 64 + c];
    } else if (tid < 3072) {                          // fcw: g in [0,32), c in [0,48)
        int t = tid - 1536; int c = t % 48, g = t / 48;
#pragma unroll
        for (int j = 0; j < 8; j++)
            fcwT[(size_t)(g * 48 + c) * 8 + j] = (c < NCLS) ? fcw[(size_t)(g * 8 + j) * NCLS + c] : (unsigned short)0;
    }
}

// ---------------------------------------------------------------------------
// CSR sort by target (targets < NUSER only).  hist records each edge's rank
// (atomicAdd return) so scatter needs no atomics.
// ---------------------------------------------------------------------------
__global__ __launch_bounds__(256) void hist3(const int* __restrict__ ei,
                                             unsigned int* __restrict__ cnt,
                                             unsigned int* __restrict__ rank)
{
    int e = blockIdx.x * 256 + threadIdx.x;
    int k = blockIdx.y;
    if (e >= EE) return;
    int tn = ei[(size_t)k * 2 * EE + EE + e];
    if (tn < NUSER)
        rank[(size_t)k * EE + e] = atomicAdd(&cnt[(size_t)k * NUSER + tn], 1u);
}

// 3-phase multi-block exclusive scan
#define SCB 20          // blocks per kind, 2048 elements each
__global__ __launch_bounds__(256) void scanA(const unsigned int* __restrict__ cnt,
                                             unsigned int* __restrict__ partials)
{
    int k = blockIdx.y, b = blockIdx.x;
    const unsigned int* c = cnt + (size_t)k * NUSER;
    int base = b * 2048 + threadIdx.x * 8;
    unsigned int s = 0;
#pragma unroll
    for (int j = 0; j < 8; j++) { int idx = base + j; if (idx < NUSER) s += c[idx]; }
#pragma unroll
    for (int off = 1; off < 64; off <<= 1) s += __shfl_xor(s, off, 64);
    __shared__ unsigned int wsum[4];
    int lane = threadIdx.x & 63, wid = threadIdx.x >> 6;
    if (lane == 0) wsum[wid] = s;
    __syncthreads();
    if (threadIdx.x == 0) partials[k * SCB + b] = wsum[0] + wsum[1] + wsum[2] + wsum[3];
}

__global__ __launch_bounds__(256) void scanB(unsigned int* __restrict__ partials,
                                             unsigned int* __restrict__ rowptr)
{
    int wid = threadIdx.x >> 6, lane = threadIdx.x & 63;
    if (wid >= KKIND) return;
    unsigned int v = (lane < SCB) ? partials[wid * SCB + lane] : 0u;
    unsigned int inc = v;
#pragma unroll
    for (int off = 1; off < 32; off <<= 1) {
        unsigned int u = __shfl_up(inc, off, 64);
        if (lane >= off) inc += u;
    }
    if (lane < SCB) partials[wid * SCB + lane] = inc - v;      // exclusive
    if (lane == SCB - 1) rowptr[(size_t)wid * (NUSER + 1) + NUSER] = inc;  // total
}

__global__ __launch_bounds__(256) void scanC(const unsigned int* __restrict__ cnt,
                                             const unsigned int* __restrict__ partials,
                                             unsigned int* __restrict__ rowptr)
{
    int k = blockIdx.y, b = blockIdx.x;
    const unsigned int* c = cnt + (size_t)k * NUSER;
    unsigned int* rp = rowptr + (size_t)k * (NUSER + 1);
    int lane = threadIdx.x & 63, wid = threadIdx.x >> 6;
    int base = b * 2048 + threadIdx.x * 8;
    unsigned int vals[8]; unsigned int s = 0;
#pragma unroll
    for (int j = 0; j < 8; j++) { int idx = base + j; vals[j] = (idx < NUSER) ? c[idx] : 0u; s += vals[j]; }
    unsigned int inc = s;
#pragma unroll
    for (int off = 1; off < 64; off <<= 1) {
        unsigned int u = __shfl_up(inc, off, 64);
        if (lane >= off) inc += u;
    }
    __shared__ unsigned int wsum[4];
    if (lane == 63) wsum[wid] = inc;
    __syncthreads();
    unsigned int woff = 0;
    for (int i = 0; i < wid; i++) woff += wsum[i];
    unsigned int run = partials[k * SCB + b] + woff + (inc - s);
#pragma unroll
    for (int j = 0; j < 8; j++) {
        int idx = base + j;
        if (idx < NUSER) { rp[idx] = run; run += vals[j]; }
    }
}

// atomic-free scatter: p = rowptr[tn] + rank[e]
__global__ __launch_bounds__(256) void scatter3(const int* __restrict__ ei,
                                                const unsigned int* __restrict__ rowptr,
                                                const unsigned int* __restrict__ rank,
                                                int* __restrict__ srcl)
{
    int e = blockIdx.x * 256 + threadIdx.x;
    int k = blockIdx.y;
    if (e >= EE) return;
    const int* srcA = ei + (size_t)k * 2 * EE;
    int tn = srcA[EE + e];
    if (tn >= NUSER) return;
    unsigned int p = rowptr[(size_t)k * (NUSER + 1) + tn] + rank[(size_t)k * EE + e];
    srcl[(size_t)k * EE + p] = srcA[e];
}

// ---------------------------------------------------------------------------
// hp2 = h @ w[k] in layout [n][f][4heads] bf16, fused s/t epilogue.
// ---------------------------------------------------------------------------
__global__ __launch_bounds__(256) void hp_gemm(const unsigned short* __restrict__ h,
                                               const unsigned short* __restrict__ wTk,
                                               const unsigned short* __restrict__ ak_src,
                                               const unsigned short* __restrict__ ak_trg,
                                               unsigned short* __restrict__ hp2,
                                               float* __restrict__ sb, float* __restrict__ tb)
{
    int wave = (blockIdx.x * 256 + threadIdx.x) >> 6;
    int lane = threadIdx.x & 63;
    if (wave >= NN / 16) return;
    int m0 = wave * 16;
    int mi = lane & 15, quad = lane >> 4;

    short8 a[4];
    const unsigned short* hrow = h + (size_t)(m0 + mi) * FIN + quad * 8;
#pragma unroll
    for (int kk = 0; kk < 4; kk++) a[kk] = *(const short8*)(hrow + kk * 32);

    float sp[4][4], tp[4][4];
#pragma unroll
    for (int r = 0; r < 4; r++)
#pragma unroll
        for (int q2 = 0; q2 < 4; q2++) { sp[r][q2] = 0.f; tp[r][q2] = 0.f; }

#pragma unroll
    for (int j = 0; j < 4; j++) {
        int fc = j * 16 + mi;
        floatx4 acc4[4];
#pragma unroll
        for (int hh = 0; hh < 4; hh++) {
            floatx4 acc = {0.f, 0.f, 0.f, 0.f};
#pragma unroll
            for (int kk = 0; kk < 4; kk++) {
                short8 b = *(const short8*)(wTk + (size_t)((hh * 16 + kk * 4 + quad) * 64 + fc) * 8);
                acc = __builtin_amdgcn_mfma_f32_16x16x32_bf16(a[kk], b, acc, 0, 0, 0);
            }
            acc4[hh] = acc;
            float asv = bf2f(ak_src[hh * 64 + fc]);
            float atv = bf2f(ak_trg[hh * 64 + fc]);
#pragma unroll
            for (int reg = 0; reg < 4; reg++) {
                sp[reg][hh] += acc[reg] * asv;
                tp[reg][hh] += acc[reg] * atv;
            }
        }
#pragma unroll
        for (int reg = 0; reg < 4; reg++) {
            ushort4 pk;
            pk.x = f2bf(acc4[0][reg]); pk.y = f2bf(acc4[1][reg]);
            pk.z = f2bf(acc4[2][reg]); pk.w = f2bf(acc4[3][reg]);
            int row = m0 + quad * 4 + reg;
            *(ushort4*)(hp2 + (size_t)row * 256 + fc * 4) = pk;
        }
    }
#pragma unroll
    for (int off = 1; off < 16; off <<= 1)
#pragma unroll
        for (int r = 0; r < 4; r++)
#pragma unroll
            for (int q2 = 0; q2 < 4; q2++) {
                sp[r][q2] += __shfl_xor(sp[r][q2], off, 64);
                tp[r][q2] += __shfl_xor(tp[r][q2], off, 64);
            }
    float sv = 0.f, tv = 0.f;
#pragma unroll
    for (int r = 0; r < 4; r++)
#pragma unroll
        for (int q2 = 0; q2 < 4; q2++) {
            bool sel = (mi == r * 4 + q2);
            sv = sel ? sp[r][q2] : sv;
            tv = sel ? tp[r][q2] : tv;
        }
    int rr = m0 + quad * 4 + (mi >> 2);
    sb[rr * 4 + (mi & 3)] = sv;
    tb[rr * 4 + (mi & 3)] = tv;
}

// ---------------------------------------------------------------------------
// passB6: wave per user node, two-phase.  Phase 1: lane j computes edge j's
// 4 exp-weights ONCE (no 64x redundancy), stores {src,e4} in wave-private
// LDS; denominators via shuffle reduction.  Phase 2: uniform-LDS-broadcast
// edge loop, coalesced hp2 row gather, 4 FMA/lane/edge.
// ---------------------------------------------------------------------------
__global__ __launch_bounds__(256) void passB6(const unsigned int* __restrict__ rowptr,
                                              const int* __restrict__ srcl,
                                              const float* __restrict__ sb,
                                              const float* __restrict__ tb,
                                              const unsigned short* __restrict__ hp2,
                                              unsigned short* __restrict__ ret, int kslice)
{
    __shared__ int   lds_src[4][64];
    __shared__ float4 lds_ew[4][64];
    int wid = threadIdx.x >> 6;
    int n = __builtin_amdgcn_readfirstlane(blockIdx.x * 4 + wid);
    int f = threadIdx.x & 63;
    unsigned int beg = rowptr[n], end = rowptr[n + 1];
    float4 t4 = *(const float4*)(tb + (size_t)n * 4);
    float num0 = 0.f, num1 = 0.f, num2 = 0.f, num3 = 0.f;
    float den0 = 0.f, den1 = 0.f, den2 = 0.f, den3 = 0.f;

    for (unsigned int p0 = beg; p0 < end; p0 += 64) {
        unsigned int cnt = end - p0; if (cnt > 64) cnt = 64;
        // ---- phase 1: one edge per lane ----
        int s = 0;
        float4 e = {0.f, 0.f, 0.f, 0.f};
        if ((unsigned int)f < cnt) {
            s = srcl[p0 + f];
            float4 sv = *(const float4*)(sb + (size_t)s * 4);
            float v0 = sv.x + t4.x, v1 = sv.y + t4.y, v2 = sv.z + t4.z, v3 = sv.w + t4.w;
            v0 = (v0 >= 0.f) ? v0 : 0.2f * v0;  v1 = (v1 >= 0.f) ? v1 : 0.2f * v1;
            v2 = (v2 >= 0.f) ? v2 : 0.2f * v2;  v3 = (v3 >= 0.f) ? v3 : 0.2f * v3;
            e.x = __expf(v0); e.y = __expf(v1); e.z = __expf(v2); e.w = __expf(v3);
        }
        lds_src[wid][f] = s;
        lds_ew[wid][f] = e;
        float d0 = e.x, d1 = e.y, d2 = e.z, d3 = e.w;
#pragma unroll
        for (int off = 1; off < 64; off <<= 1) {
            d0 += __shfl_xor(d0, off, 64); d1 += __shfl_xor(d1, off, 64);
            d2 += __shfl_xor(d2, off, 64); d3 += __shfl_xor(d3, off, 64);
        }
        den0 += d0; den1 += d1; den2 += d2; den3 += d3;
        // ---- phase 2: broadcast edge loop, 8-wide ----
        unsigned int jmax = (cnt + 7u) & ~7u;
        for (unsigned int j = 0; j < jmax; j += 8) {
            int ss[8]; float4 ee[8];
#pragma unroll
            for (int u = 0; u < 8; u++) { ss[u] = lds_src[wid][j + u]; ee[u] = lds_ew[wid][j + u]; }
            ushort4 hv[8];
#pragma unroll
            for (int u = 0; u < 8; u++) hv[u] = *(const ushort4*)(hp2 + (size_t)ss[u] * 256 + f * 4);
#pragma unroll
            for (int u = 0; u < 8; u++) {
                num0 += ee[u].x * bf2f(hv[u].x); num1 += ee[u].y * bf2f(hv[u].y);
                num2 += ee[u].z * bf2f(hv[u].z); num3 += ee[u].w * bf2f(hv[u].w);
            }
        }
    }
    float r = 0.25f * (num0 / (den0 + 1e-16f) + num1 / (den1 + 1e-16f)
                     + num2 / (den2 + 1e-16f) + num3 / (den3 + 1e-16f));
    ret[(size_t)n * 256 + kslice * 64 + f] = f2bf(r);
}

// ---------------------------------------------------------------------------
// qscore2: per 16-row tile, fw1 = h@w1 in-register; per k: scores = tanh(..).m
// ---------------------------------------------------------------------------
__global__ __launch_bounds__(256) void qscore2(const unsigned short* __restrict__ h,
                                               const unsigned short* __restrict__ w1T,
                                               const unsigned short* __restrict__ retA,
                                               const unsigned short* __restrict__ w2T,
                                               const unsigned short* __restrict__ mvec,
                                               float* __restrict__ scores, int M)
{
    int wave = (blockIdx.x * 256 + threadIdx.x) >> 6;
    int lane = threadIdx.x & 63;
    int m0 = wave * 16;
    if (m0 >= M) return;
    int mi = lane & 15, quad = lane >> 4;

    floatx4 fw[4];
#pragma unroll
    for (int nt = 0; nt < 4; nt++) fw[nt] = (floatx4){0.f, 0.f, 0.f, 0.f};
#pragma unroll
    for (int kk = 0; kk < 4; kk++) {
        short8 a = *(const short8*)(h + (size_t)(m0 + mi) * FIN + kk * 32 + quad * 8);
#pragma unroll
        for (int nt = 0; nt < 4; nt++) {
            short8 b = *(const short8*)(w1T + (size_t)((kk * 4 + quad) * 64 + nt * 16 + mi) * 8);
            fw[nt] = __builtin_amdgcn_mfma_f32_16x16x32_bf16(a, b, fw[nt], 0, 0, 0);
        }
    }

    for (int k = 0; k < KKIND; k++) {
        floatx4 acc[4];
#pragma unroll
        for (int nt = 0; nt < 4; nt++) acc[nt] = (floatx4){0.f, 0.f, 0.f, 0.f};
#pragma unroll
        for (int kk = 0; kk < 2; kk++) {
            short8 a = *(const short8*)(retA + (size_t)(m0 + mi) * 256 + k * 64 + kk * 32 + quad * 8);
#pragma unroll
            for (int nt = 0; nt < 4; nt++) {
                short8 b = *(const short8*)(w2T + (size_t)((kk * 4 + quad) * 64 + nt * 16 + mi) * 8);
                acc[nt] = __builtin_amdgcn_mfma_f32_16x16x32_bf16(a, b, acc[nt], 0, 0, 0);
            }
        }
        float part[4] = {0.f, 0.f, 0.f, 0.f};
#pragma unroll
        for (int nt = 0; nt < 4; nt++) {
            int col = nt * 16 + mi;
            float mval = bf2f(mvec[col]);
#pragma unroll
            for (int reg = 0; reg < 4; reg++) {
                float x = acc[nt][reg] + fw[nt][reg];
                float q = 1.f - 2.f / (1.f + __expf(2.f * x));   // tanh, NaN-free
                part[reg] += q * mval;
            }
        }
#pragma unroll
        for (int off = 1; off < 16; off <<= 1)
#pragma unroll
            for (int reg = 0; reg < 4; reg++) part[reg] += __shfl_xor(part[reg], off, 64);
        if (mi == 0) {
#pragma unroll
            for (int reg = 0; reg < 4; reg++)
                scores[(size_t)(m0 + quad * 4 + reg) * 3 + k] = part[reg];
        }
    }
}

// ---------------------------------------------------------------------------
// beta = softmax(scores); ret[:,192:256] = bf16(sum_k beta_k * ret_k)
// ---------------------------------------------------------------------------
__global__ __launch_bounds__(256) void fuse_kernel(const float* __restrict__ scores,
                                                   unsigned short* __restrict__ ret)
{
    int n = blockIdx.x * 4 + (threadIdx.x >> 6);
    int f = threadIdx.x & 63;
    float s0 = scores[n * 3 + 0], s1 = scores[n * 3 + 1], s2 = scores[n * 3 + 2];
    float mx = fmaxf(s0, fmaxf(s1, s2));
    float e0 = __expf(s0 - mx), e1 = __expf(s1 - mx), e2 = __expf(s2 - mx);
    float inv = 1.f / (e0 + e1 + e2);
    const unsigned short* row = ret + (size_t)n * 256;
    float fu = (e0 * bf2f(row[f]) + e1 * bf2f(row[64 + f]) + e2 * bf2f(row[128 + f])) * inv;
    ret[(size_t)n * 256 + 192 + f] = f2bf(fu);
}

// ---------------------------------------------------------------------------
// logits = ret(M x 256) @ fcwT + bias, fused log_softmax -> out (dtype per flag)
// ---------------------------------------------------------------------------
__global__ __launch_bounds__(256) void fc_lsm(const unsigned short* __restrict__ A,
                                              const unsigned short* __restrict__ fcwT,
                                              const unsigned short* __restrict__ bias,
                                              const int* __restrict__ flagp,
                                              void* __restrict__ out, int M)
{
    int wave = (blockIdx.x * 256 + threadIdx.x) >> 6;
    int lane = threadIdx.x & 63;
    int m0 = wave * 16;
    if (m0 >= M) return;
    int mi = lane & 15, quad = lane >> 4;
    floatx4 acc[3];
#pragma unroll
    for (int nt = 0; nt < 3; nt++) acc[nt] = (floatx4){0.f, 0.f, 0.f, 0.f};
#pragma unroll
    for (int kk = 0; kk < 8; kk++) {
        short8 a = *(const short8*)(A + (size_t)(m0 + mi) * 256 + kk * 32 + quad * 8);
#pragma unroll
        for (int nt = 0; nt < 3; nt++) {
            short8 b = *(const short8*)(fcwT + (size_t)((kk * 4 + quad) * 48 + nt * 16 + mi) * 8);
            acc[nt] = __builtin_amdgcn_mfma_f32_16x16x32_bf16(a, b, acc[nt], 0, 0, 0);
        }
    }
    int fl = *flagp;
    float bv[3]; bool ok[3];
#pragma unroll
    for (int nt = 0; nt < 3; nt++) {
        int col = nt * 16 + mi;
        ok[nt] = (col < NCLS);
        bv[nt] = ok[nt] ? bf2f(bias[col]) : 0.f;
    }
#pragma unroll
    for (int reg = 0; reg < 4; reg++) {
        float v[3];
#pragma unroll
        for (int nt = 0; nt < 3; nt++)
            v[nt] = ok[nt] ? (acc[nt][reg] + bv[nt]) : -3.4e38f;
        float mx = fmaxf(fmaxf(v[0], v[1]), v[2]);
#pragma unroll
        for (int off = 1; off < 16; off <<= 1) mx = fmaxf(mx, __shfl_xor(mx, off, 64));
        float s = 0.f;
#pragma unroll
        for (int nt = 0; nt < 3; nt++) s += ok[nt] ? __expf(v[nt] - mx) : 0.f;
#pragma unroll
        for (int off = 1; off < 16; off <<= 1) s += __shfl_xor(s, off, 64);
        float lse = mx + __logf(s);
        int row = m0 + quad * 4 + reg;
#pragma unroll
        for (int nt = 0; nt < 3; nt++) {
            int col = nt * 16 + mi;
            if (col < NCLS) {
                float ls = v[nt] - lse;
                size_t idx = (size_t)row * NCLS + col;
                if (fl) ((float*)out)[idx] = ls;
                else    ((unsigned short*)out)[idx] = f2bf(ls);
            }
        }
    }
}

extern "C" void kernel_launch(void* const* d_in, const int* in_sizes, int n_in,
                              void* d_out, int out_size, void* d_ws, size_t ws_size,
                              hipStream_t stream)
{
    (void)in_sizes; (void)n_in; (void)out_size; (void)ws_size;
    const int* ei = (const int*)d_in[1];

    char* ws = (char*)d_ws;
    unsigned short* conv = (unsigned short*)ws;                 // 13,044,944 B
    unsigned short* hc   = conv + OFF_H;
    unsigned short* wc   = conv + OFF_W;
    unsigned short* asrc = conv + OFF_ASRC;
    unsigned short* atrg = conv + OFF_ATRG;
    unsigned short* w1c  = conv + OFF_W1;
    unsigned short* w2c  = conv + OFF_W2;
    unsigned short* mc   = conv + OFF_M;
    unsigned short* fcwc = conv + OFF_FCW;
    unsigned short* fcbc = conv + OFF_FCB;
    int* flag             = (int*)(ws + 13044944);
    unsigned short* wT    = (unsigned short*)(ws + 13045248);   //    196,608 B
    unsigned short* w1T   = (unsigned short*)(ws + 13241856);   //     16,384 B
    unsigned short* w2T   = (unsigned short*)(ws + 13258240);   //      8,192 B
    unsigned short* fcwT  = (unsigned short*)(ws + 13266432);   //     24,576 B
    unsigned int* partials= (unsigned int*)(ws + 13291008);     //        256 B
    unsigned int* cnt     = (unsigned int*)(ws + 13291264);     //    480,000 B
    float* scores         = (float*)(ws + 13291264);            // overlay (cnt dead post-scan)
    unsigned int* rowptr  = (unsigned int*)(ws + 13771264);     //    480,256 B
    int* srcl             = (int*)(ws + 14251520);              //  4,800,000 B
    unsigned int* rank    = (unsigned int*)(ws + 19051520);     //  4,800,000 B
    float* sbuf           = (float*)(ws + 23851520);            //    800,000 B
    float* tbuf           = (float*)(ws + 24651520);            //    800,000 B
    unsigned short* hp2   = (unsigned short*)(ws + 25451520);   // 25,600,000 B
    unsigned short* ret   = (unsigned short*)(ws + 51051520);   // 20,480,000 B -> 71,531,520

    detect_kernel<<<1, 256, 0, stream>>>((const unsigned short*)d_in[0], flag);
    conv_kernel<<<(CONV_TOT / 8 + 255) / 256, 256, 0, stream>>>(
        d_in[0], d_in[2], d_in[3], d_in[4], d_in[5], d_in[6], d_in[7], d_in[8], d_in[9],
        flag, conv);

    repack_w<<<48, 256, 0, stream>>>(wc, wT);
    repack_small<<<12, 256, 0, stream>>>(w1c, w2c, fcwc, w1T, w2T, fcwT);

    hipMemsetAsync(cnt, 0, (size_t)KKIND * NUSER * 4, stream);
    hist3<<<dim3(1563, 3), 256, 0, stream>>>(ei, cnt, rank);
    scanA<<<dim3(SCB, 3), 256, 0, stream>>>(cnt, partials);
    scanB<<<1, 256, 0, stream>>>(partials, rowptr);
    scanC<<<dim3(SCB, 3), 256, 0, stream>>>(cnt, partials, rowptr);
    scatter3<<<dim3(1563, 3), 256, 0, stream>>>(ei, rowptr, rank, srcl);

    for (int k = 0; k < KKIND; k++) {
        hp_gemm<<<782, 256, 0, stream>>>(hc, wT + (size_t)k * 32768,
                                         asrc + k * HHEAD * FOUT, atrg + k * HHEAD * FOUT,
                                         hp2, sbuf, tbuf);
        passB6<<<NUSER / 4, 256, 0, stream>>>(rowptr + (size_t)k * (NUSER + 1),
                                              srcl + (size_t)k * EE,
                                              sbuf, tbuf, hp2, ret, k);
    }

    qscore2<<<625, 256, 0, stream>>>(hc, w1T, ret, w2T, mc, scores, NUSER);
    fuse_kernel<<<NUSER / 4, 256, 0, stream>>>(scores, ret);
    fc_lsm<<<625, 256, 0, stream>>>(ret, fcwT, fcbc, flag, d_out, NUSER);
}